// Round 8
// baseline (1128.261 us; speedup 1.0000x reference)
//
#include <hip/hip_runtime.h>

#define N_NODES 150000
#define N_EDGES 2400000
#define N_GRAPHS 1024
#define F 32
#define EPSV 1e-5f

#define BS 128                                   // nodes per dst-bucket
#define NB ((N_NODES + BS - 1) / BS)             // 1172 buckets
#define EB 4096                                  // edges per binning block
#define NEB ((N_EDGES + EB - 1) / EB)            // 586 blocks
#define EPT (EB / 256)                           // 16 edges per thread
#define SPT ((NB + 255) / 256)                   // scan items per thread (5)

// bf16 helpers (RTN-even encode; decode via shift/mask)
__device__ __forceinline__ float bflo(unsigned int u) {
    union { unsigned int i; float f; } v; v.i = u << 16; return v.f;
}
__device__ __forceinline__ float bfhi(unsigned int u) {
    union { unsigned int i; float f; } v; v.i = u & 0xffff0000u; return v.f;
}
__device__ __forceinline__ unsigned int f2bf(float f) {
    union { float f; unsigned int i; } v; v.f = f;
    unsigned int r = v.i + 0x7fff + ((v.i >> 16) & 1);
    return r >> 16;
}

// ---------------------------------------------------------------------------
// K0: graph offsets from sorted batch; zero bucket histogram
// ---------------------------------------------------------------------------
__global__ void k_init(const int* __restrict__ batch, int* __restrict__ bucketCnt,
                       int* __restrict__ off) {
    int i = blockIdx.x * blockDim.x + threadIdx.x;
    if (i >= N_NODES) return;
    if (i < NB) bucketCnt[i] = 0;
    int b = batch[i];
    if (i == 0) {
        for (int g = 0; g <= b; ++g) off[g] = 0;
    } else {
        int pb = batch[i - 1];
        for (int g = pb + 1; g <= b; ++g) off[g] = i;
    }
    if (i == N_NODES - 1) {
        for (int g = b + 1; g <= N_GRAPHS; ++g) off[g] = N_NODES;
    }
}

// ---------------------------------------------------------------------------
// K1: bucket histogram (LDS-aggregated, well-distributed addresses)
// ---------------------------------------------------------------------------
__global__ __launch_bounds__(256) void k_bhist(const int* __restrict__ dst,
                                               int* __restrict__ bucketCnt) {
    __shared__ int h[NB];
    int t = threadIdx.x;
    for (int b = t; b < NB; b += 256) h[b] = 0;
    __syncthreads();
    int base = blockIdx.x * EB + t;
#pragma unroll
    for (int k = 0; k < EPT; ++k) {
        int e = base + k * 256;
        if (e < N_EDGES) atomicAdd(&h[dst[e] >> 7], 1);
    }
    __syncthreads();
    for (int b = t; b < NB; b += 256) {
        int c = h[b];
        if (c) atomicAdd(&bucketCnt[b], c);
    }
}

// ---------------------------------------------------------------------------
// K2: exclusive scan of bucket counts -> offsets + cursors
// ---------------------------------------------------------------------------
__global__ __launch_bounds__(256) void k_bscan(const int* __restrict__ bucketCnt,
                                               int* __restrict__ bucketOff,
                                               int* __restrict__ bucketCur) {
    __shared__ int sc[256];
    int t = threadIdx.x;
    int v[SPT];
    int s = 0;
#pragma unroll
    for (int k = 0; k < SPT; ++k) {
        int i = t * SPT + k;
        v[k] = (i < NB) ? bucketCnt[i] : 0;
        s += v[k];
    }
    sc[t] = s;
    __syncthreads();
    for (int o = 1; o < 256; o <<= 1) {
        int x = (t >= o) ? sc[t - o] : 0;
        __syncthreads();
        sc[t] += x;
        __syncthreads();
    }
    int run = sc[t] - s;
#pragma unroll
    for (int k = 0; k < SPT; ++k) {
        int i = t * SPT + k;
        if (i < NB) { bucketOff[i] = run; bucketCur[i] = run; }
        run += v[k];
    }
    if (t == 0) bucketOff[NB] = N_EDGES;
}

// ---------------------------------------------------------------------------
// K3: bin edges into buckets. key = (localdst << 18) | src  (7b + 18b)
// ---------------------------------------------------------------------------
__global__ __launch_bounds__(256) void k_bin(const int* __restrict__ src,
                                             const int* __restrict__ dst,
                                             int* __restrict__ bucketCur,
                                             unsigned int* __restrict__ binned) {
    __shared__ int h[NB];
    __shared__ int gb[NB];
    int t = threadIdx.x;
    for (int b = t; b < NB; b += 256) h[b] = 0;
    __syncthreads();
    int base = blockIdx.x * EB + t;
    unsigned int key[EPT];
    int rk[EPT], bk[EPT];
#pragma unroll
    for (int k = 0; k < EPT; ++k) {
        int e = base + k * 256;
        if (e < N_EDGES) {
            int d = dst[e];
            int b = d >> 7;
            bk[k] = b;
            key[k] = ((unsigned int)(d & 127) << 18) | (unsigned int)src[e];
            rk[k] = atomicAdd(&h[b], 1);
        } else {
            bk[k] = -1;
        }
    }
    __syncthreads();
    for (int b = t; b < NB; b += 256) {
        int c = h[b];
        gb[b] = c ? atomicAdd(&bucketCur[b], c) : 0;
    }
    __syncthreads();
#pragma unroll
    for (int k = 0; k < EPT; ++k)
        if (bk[k] >= 0) binned[gb[bk[k]] + rk[k]] = key[k];
}

// ---------------------------------------------------------------------------
// K4: per-bucket degree -> dinv + xs = x*dinv
// ---------------------------------------------------------------------------
__global__ __launch_bounds__(256) void k_ndeg(const unsigned int* __restrict__ binned,
                                              const int* __restrict__ bucketOff,
                                              const float* __restrict__ x,
                                              float* __restrict__ dinv,
                                              float* __restrict__ xs) {
    __shared__ int cnt[BS];
    int b = blockIdx.x, t = threadIdx.x;
    if (t < BS) cnt[t] = 0;
    __syncthreads();
    int e0 = bucketOff[b], e1 = bucketOff[b + 1];
    for (int e = e0 + t; e < e1; e += 256)
        atomicAdd(&cnt[binned[e] >> 18], 1);
    __syncthreads();
    if (t < BS) {
        int n = b * BS + t;
        if (n < N_NODES) {
            float dv = rsqrtf((float)cnt[t] + 1.0f);
            dinv[n] = dv;
            xs[n * 3 + 0] = x[n * 3 + 0] * dv;
            xs[n * 3 + 1] = x[n * 3 + 1] * dv;
            xs[n * 3 + 2] = x[n * 3 + 2] * dv;
        }
    }
}

// ---------------------------------------------------------------------------
// K5a: layer-1 bucket-resident edge-centric aggregate(3-wide) + 3->32
// transform + bias. One block per bucket; LDS fp32 accumulator (stride 5
// to spread banks); 1 thread per edge.
// ---------------------------------------------------------------------------
__global__ __launch_bounds__(256) void k_agg3(
        const unsigned int* __restrict__ binned, const int* __restrict__ bucketOff,
        const float* __restrict__ xs, const float* __restrict__ dinv,
        const float* __restrict__ W, const float* __restrict__ bias,
        float* __restrict__ y) {
    __shared__ float acc[BS * 5];
    __shared__ float ws[3 * F], bs[F];
    int b = blockIdx.x, t = threadIdx.x;
    for (int i = t; i < BS * 5; i += 256) acc[i] = 0.f;
    if (t < 96) ws[t] = W[t];
    if (t < F) bs[t] = bias[t];
    __syncthreads();
    int e0 = bucketOff[b], e1 = bucketOff[b + 1];
    for (int e = e0 + t; e < e1; e += 256) {
        unsigned int key = binned[e];
        int s = key & 0x3FFFF, ld = key >> 18;
        atomicAdd(&acc[ld * 5 + 0], xs[s * 3 + 0]);
        atomicAdd(&acc[ld * 5 + 1], xs[s * 3 + 1]);
        atomicAdd(&acc[ld * 5 + 2], xs[s * 3 + 2]);
    }
    __syncthreads();
    int ln = t >> 1, h = t & 1;
    int n = b * BS + ln;
    if (n < N_NODES) {
        float dd = dinv[n];
        float z0 = dd * (acc[ln * 5 + 0] + xs[n * 3 + 0]);
        float z1 = dd * (acc[ln * 5 + 1] + xs[n * 3 + 1]);
        float z2 = dd * (acc[ln * 5 + 2] + xs[n * 3 + 2]);
#pragma unroll
        for (int q = 0; q < 4; ++q) {
            int f = h * 16 + q * 4;
            float4 w0 = *(float4*)&ws[0 * F + f];
            float4 w1 = *(float4*)&ws[1 * F + f];
            float4 w2 = *(float4*)&ws[2 * F + f];
            float4 o  = *(float4*)&bs[f];
            o.x += z0 * w0.x + z1 * w1.x + z2 * w2.x;
            o.y += z0 * w0.y + z1 * w1.y + z2 * w2.y;
            o.z += z0 * w0.z + z1 * w1.z + z2 * w2.z;
            o.w += z0 * w0.w + z1 * w1.w + z2 * w2.w;
            ((float4*)y)[n * 8 + h * 4 + q] = o;
        }
    }
}

// ---------------------------------------------------------------------------
// K5b: bucket-resident edge-centric aggregate(32-wide bf16 rows) + 32->32
// transform + bias. One block per bucket; acc[128][33] fp32 in LDS (stride 33
// -> bank-spread LDS atomics); 4 lanes/edge, 2x unrolled; epilogue adds the
// self row and applies W from LDS.
// ---------------------------------------------------------------------------
__global__ __launch_bounds__(256) void k_agg32(
        const unsigned int* __restrict__ binned, const int* __restrict__ bucketOff,
        const unsigned short* __restrict__ xh, const float* __restrict__ dinv,
        const float* __restrict__ W, const float* __restrict__ bias,
        float* __restrict__ y) {
    __shared__ float Ws[F * F];      // 4 KB
    __shared__ float bs[F];
    __shared__ float acc[BS * 33];   // 16.5 KB
    int b = blockIdx.x, t = threadIdx.x;
    ((float4*)Ws)[t] = ((const float4*)W)[t];
    if (t < F) bs[t] = bias[t];
    for (int i = t; i < BS * 33; i += 256) acc[i] = 0.f;
    __syncthreads();

    int e0 = bucketOff[b], e1 = bucketOff[b + 1];
    const uint4* xr = (const uint4*)xh;  // one row = 4 x 16B
    int c = t & 3, eg = t >> 2;          // 64 edge-groups, 4 lanes each
    int iters = (e1 - e0 + 127) >> 7;    // 2 edges per group per iter
    for (int it = 0; it < iters; ++it) {
        int eA = e0 + it * 128 + eg;
        int eB = eA + 64;
        bool vA = eA < e1, vB = eB < e1;
        unsigned int keyA = vA ? binned[eA] : 0u;
        unsigned int keyB = vB ? binned[eB] : 0u;
        uint4 uA, uB;
        if (vA) uA = xr[(keyA & 0x3FFFF) * 4 + c];
        if (vB) uB = xr[(keyB & 0x3FFFF) * 4 + c];
        if (vA) {
            float* ap = &acc[(keyA >> 18) * 33 + c * 8];
            atomicAdd(ap + 0, bflo(uA.x)); atomicAdd(ap + 1, bfhi(uA.x));
            atomicAdd(ap + 2, bflo(uA.y)); atomicAdd(ap + 3, bfhi(uA.y));
            atomicAdd(ap + 4, bflo(uA.z)); atomicAdd(ap + 5, bfhi(uA.z));
            atomicAdd(ap + 6, bflo(uA.w)); atomicAdd(ap + 7, bfhi(uA.w));
        }
        if (vB) {
            float* ap = &acc[(keyB >> 18) * 33 + c * 8];
            atomicAdd(ap + 0, bflo(uB.x)); atomicAdd(ap + 1, bfhi(uB.x));
            atomicAdd(ap + 2, bflo(uB.y)); atomicAdd(ap + 3, bfhi(uB.y));
            atomicAdd(ap + 4, bflo(uB.z)); atomicAdd(ap + 5, bfhi(uB.z));
            atomicAdd(ap + 6, bflo(uB.w)); atomicAdd(ap + 7, bfhi(uB.w));
        }
    }
    __syncthreads();

    // add self row (dd^2*x = dd*xh): 2 threads/node, disjoint halves
    int ln = t >> 1, h = t & 1;
    int n = b * BS + ln;
    if (n < N_NODES) {
        uint4 s0 = xr[n * 4 + h * 2];
        uint4 s1 = xr[n * 4 + h * 2 + 1];
        float* ap = &acc[ln * 33 + h * 16];
        ap[0] += bflo(s0.x); ap[1] += bfhi(s0.x);
        ap[2] += bflo(s0.y); ap[3] += bfhi(s0.y);
        ap[4] += bflo(s0.z); ap[5] += bfhi(s0.z);
        ap[6] += bflo(s0.w); ap[7] += bfhi(s0.w);
        ap[8]  += bflo(s1.x); ap[9]  += bfhi(s1.x);
        ap[10] += bflo(s1.y); ap[11] += bfhi(s1.y);
        ap[12] += bflo(s1.z); ap[13] += bfhi(s1.z);
        ap[14] += bflo(s1.w); ap[15] += bfhi(s1.w);
    }
    __syncthreads();

    if (n < N_NODES) {
        float dd = dinv[n];
        float4 o0 = ((const float4*)bs)[h * 4 + 0];
        float4 o1 = ((const float4*)bs)[h * 4 + 1];
        float4 o2 = ((const float4*)bs)[h * 4 + 2];
        float4 o3 = ((const float4*)bs)[h * 4 + 3];
        const float* arow = &acc[ln * 33];
#pragma unroll
        for (int k = 0; k < F; ++k) {
            float zk = arow[k] * dd;
            const float4* wr = (const float4*)&Ws[k * F];
            float4 w0 = wr[h * 4 + 0], w1 = wr[h * 4 + 1];
            float4 w2 = wr[h * 4 + 2], w3 = wr[h * 4 + 3];
            o0.x += zk * w0.x; o0.y += zk * w0.y; o0.z += zk * w0.z; o0.w += zk * w0.w;
            o1.x += zk * w1.x; o1.y += zk * w1.y; o1.z += zk * w1.z; o1.w += zk * w1.w;
            o2.x += zk * w2.x; o2.y += zk * w2.y; o2.z += zk * w2.z; o2.w += zk * w2.w;
            o3.x += zk * w3.x; o3.y += zk * w3.y; o3.z += zk * w3.z; o3.w += zk * w3.w;
        }
        float4* yp = (float4*)y + n * 8 + h * 4;
        yp[0] = o0; yp[1] = o1; yp[2] = o2; yp[3] = o3;
    }
}

// ---------------------------------------------------------------------------
// K6: GraphNorm, block per graph; single-pass stats (sum/sumsq), normalize
// pass re-reads the ~19KB graph slice L2-hot. In-place capable. Emits fp32
// out + (WXH) bf16 dinv-pre-scaled xh.
// ---------------------------------------------------------------------------
template <bool RES, bool WXH>
__global__ __launch_bounds__(256) void k_gn2(
        const float* agg, const float* res, const int* __restrict__ off,
        const float* __restrict__ gw, const float* __restrict__ gb,
        const float* __restrict__ gms, const float* __restrict__ dinv,
        unsigned short* __restrict__ xh, float* outp) {
    __shared__ float red1[256], red2[256];
    __shared__ float mv_s[F], sc_s[F];
    int g = blockIdx.x;
    int i0 = off[g], i1 = off[g + 1];
    float rc = 1.0f / (float)(i1 - i0);
    int t = threadIdx.x;
    int f = t & 31, r0 = t >> 5;

    float s = 0.f, q = 0.f;
    for (int n = i0 + r0; n < i1; n += 8) {
        float v = agg[n * F + f];
        s += v; q += v * v;
    }
    red1[t] = s; red2[t] = q; __syncthreads();
    if (t < 128) { red1[t] += red1[t + 128]; red2[t] += red2[t + 128]; } __syncthreads();
    if (t < 64)  { red1[t] += red1[t + 64];  red2[t] += red2[t + 64];  } __syncthreads();
    if (t < 32) {
        float sm = (red1[t] + red1[t + 32]) * rc;
        float sq = (red2[t] + red2[t + 32]) * rc;
        float mv = gms[t] * sm;
        float var = sq - mv * (2.f * sm - mv);
        mv_s[t] = mv;
        sc_s[t] = gw[t] * rsqrtf(var + EPSV);
    }
    __syncthreads();

    float w = sc_s[f], mv = mv_s[f], bb = gb[f];
    for (int n = i0 + r0; n < i1; n += 8) {
        float y = (agg[n * F + f] - mv) * w + bb;
        if (RES) y += res[n * F + f];
        y = fmaxf(y, 0.f);
        outp[n * F + f] = y;
        if (WXH) xh[n * F + f] = (unsigned short)f2bf(y * dinv[n]);
    }
}

// ---------------------------------------------------------------------------
// K7: final GraphNorm + residual + ReLU + mean-pool + 32x3 linear
// ---------------------------------------------------------------------------
__global__ __launch_bounds__(256) void k_gnfin(
        const float* __restrict__ agg, const float* __restrict__ res,
        const int* __restrict__ off,
        const float* __restrict__ gw, const float* __restrict__ gb,
        const float* __restrict__ gms,
        const float* __restrict__ lin_w, const float* __restrict__ lin_b,
        float* __restrict__ outp) {
    __shared__ float red1[256], red2[256];
    __shared__ float mv_s[F], sc_s[F], pooled_s[F];
    int g = blockIdx.x;
    int i0 = off[g], i1 = off[g + 1];
    float cnt = (float)(i1 - i0);
    float rc = 1.0f / cnt;
    int t = threadIdx.x;
    int f = t & 31, r0 = t >> 5;

    float s = 0.f, q = 0.f;
    for (int n = i0 + r0; n < i1; n += 8) {
        float v = agg[n * F + f];
        s += v; q += v * v;
    }
    red1[t] = s; red2[t] = q; __syncthreads();
    if (t < 128) { red1[t] += red1[t + 128]; red2[t] += red2[t + 128]; } __syncthreads();
    if (t < 64)  { red1[t] += red1[t + 64];  red2[t] += red2[t + 64];  } __syncthreads();
    if (t < 32) {
        float sm = (red1[t] + red1[t + 32]) * rc;
        float sq = (red2[t] + red2[t + 32]) * rc;
        float mv = gms[t] * sm;
        float var = sq - mv * (2.f * sm - mv);
        mv_s[t] = mv;
        sc_s[t] = gw[t] * rsqrtf(var + EPSV);
    }
    __syncthreads();

    float w = sc_s[f], mv = mv_s[f], bb = gb[f];
    float ps = 0.f;
    for (int n = i0 + r0; n < i1; n += 8) {
        float yv = (agg[n * F + f] - mv) * w + bb + res[n * F + f];
        ps += fmaxf(yv, 0.f);
    }
    __syncthreads();
    red1[t] = ps; __syncthreads();
    if (t < 128) red1[t] += red1[t + 128]; __syncthreads();
    if (t < 64)  red1[t] += red1[t + 64];  __syncthreads();
    if (t < 32) { red1[t] += red1[t + 32]; pooled_s[t] = red1[t] * rc; }
    __syncthreads();
    if (t < 3) {
        float o = lin_b[t];
#pragma unroll
        for (int f2 = 0; f2 < F; ++f2) o += pooled_s[f2] * lin_w[f2 * 3 + t];
        outp[g * 3 + t] = o;
    }
}

// ---------------------------------------------------------------------------
extern "C" void kernel_launch(void* const* d_in, const int* in_sizes, int n_in,
                              void* d_out, int out_size, void* d_ws, size_t ws_size,
                              hipStream_t stream) {
    const float* x      = (const float*)d_in[0];
    const int*   ei     = (const int*)d_in[1];
    const int*   batch  = (const int*)d_in[2];
    const float* W1     = (const float*)d_in[3];
    const float* b1     = (const float*)d_in[4];
    const float* gn1w   = (const float*)d_in[5];
    const float* gn1b   = (const float*)d_in[6];
    const float* gn1ms  = (const float*)d_in[7];
    const float* W2     = (const float*)d_in[8];
    const float* b2     = (const float*)d_in[9];
    const float* gn2w   = (const float*)d_in[10];
    const float* gn2b   = (const float*)d_in[11];
    const float* gn2ms  = (const float*)d_in[12];
    const float* W3     = (const float*)d_in[13];
    const float* b3     = (const float*)d_in[14];
    const float* gn3w   = (const float*)d_in[15];
    const float* gn3b   = (const float*)d_in[16];
    const float* gn3ms  = (const float*)d_in[17];
    const float* lin_w  = (const float*)d_in[18];
    const float* lin_b  = (const float*)d_in[19];
    float* out = (float*)d_out;

    const int* srcp = ei;
    const int* dstp = ei + N_EDGES;

    char* ws = (char*)d_ws;
    size_t p = 0;
    auto alloc = [&](size_t bytes) {
        size_t r = p; p += (bytes + 511) & ~(size_t)511; return r;
    };
    int*   off       = (int*)  (ws + alloc(sizeof(int) * (N_GRAPHS + 1)));
    int*   bucketCnt = (int*)  (ws + alloc(sizeof(int) * NB));
    int*   bucketOff = (int*)  (ws + alloc(sizeof(int) * (NB + 1)));
    int*   bucketCur = (int*)  (ws + alloc(sizeof(int) * NB));
    float* dinv      = (float*)(ws + alloc(sizeof(float) * N_NODES));
    float* xs        = (float*)(ws + alloc(sizeof(float) * N_NODES * 3));
    unsigned int* binned = (unsigned int*)(ws + alloc(sizeof(unsigned int) * N_EDGES));
    unsigned short* xh = (unsigned short*)(ws + alloc(sizeof(unsigned short) * N_NODES * F));
    float* A         = (float*)(ws + alloc(sizeof(float) * N_NODES * F));
    float* B         = (float*)(ws + alloc(sizeof(float) * N_NODES * F));
    (void)ws_size; (void)n_in; (void)in_sizes; (void)out_size;

    const int TB = 256;
    dim3 blk(TB);
    int ngrid = (N_NODES + TB - 1) / TB;

    // bucketed edge sort (binned stays live as the gather edge list)
    k_init <<<ngrid, blk, 0, stream>>>(batch, bucketCnt, off);
    k_bhist<<<NEB, blk, 0, stream>>>(dstp, bucketCnt);
    k_bscan<<<1, blk, 0, stream>>>(bucketCnt, bucketOff, bucketCur);
    k_bin  <<<NEB, blk, 0, stream>>>(srcp, dstp, bucketCur, binned);
    k_ndeg <<<NB, blk, 0, stream>>>(binned, bucketOff, x, dinv, xs);

    // layer 1: bucket gather+transform -> A ; GN in-place -> x1=A (+ bf16 xh)
    k_agg3 <<<NB, blk, 0, stream>>>(binned, bucketOff, xs, dinv, W1, b1, A);
    k_gn2<false, true><<<N_GRAPHS, blk, 0, stream>>>(
        A, nullptr, off, gn1w, gn1b, gn1ms, dinv, xh, A);

    // layer 2: bucket gather(xh)+transform -> B ; GN + res(A) -> x2=B (+ xh)
    k_agg32<<<NB, blk, 0, stream>>>(binned, bucketOff, xh, dinv, W2, b2, B);
    k_gn2<true, true><<<N_GRAPHS, blk, 0, stream>>>(
        B, A, off, gn2w, gn2b, gn2ms, dinv, xh, B);

    // layer 3: bucket gather(xh)+transform -> A ; GN + res(B) + pool + linear
    k_agg32<<<NB, blk, 0, stream>>>(binned, bucketOff, xh, dinv, W3, b3, A);
    k_gnfin<<<N_GRAPHS, blk, 0, stream>>>(A, B, off, gn3w, gn3b, gn3ms,
                                          lin_w, lin_b, out);
}

// Round 9
// 353.016 us; speedup vs baseline: 3.1961x; 3.1961x over previous
//
#include <hip/hip_runtime.h>

#define N_NODES 150000
#define N_EDGES 2400000
#define N_GRAPHS 1024
#define F 32
#define EPSV 1e-5f

#define BS 256                                   // nodes per dst-bucket
#define NB ((N_NODES + BS - 1) / BS)             // 586 buckets
#define EB 4096                                  // edges per binning block
#define NEB ((N_EDGES + EB - 1) / EB)            // 586 blocks
#define EPT (EB / 256)                           // 16 edges per thread

// bf16 helpers (RTN-even encode; decode via shift/mask)
__device__ __forceinline__ float bflo(unsigned int u) {
    union { unsigned int i; float f; } v; v.i = u << 16; return v.f;
}
__device__ __forceinline__ float bfhi(unsigned int u) {
    union { unsigned int i; float f; } v; v.i = u & 0xffff0000u; return v.f;
}
__device__ __forceinline__ unsigned int f2bf(float f) {
    union { float f; unsigned int i; } v; v.f = f;
    unsigned int r = v.i + 0x7fff + ((v.i >> 16) & 1);
    return r >> 16;
}

// ---------------------------------------------------------------------------
// K0: graph offsets from sorted batch; zero bucket histogram
// ---------------------------------------------------------------------------
__global__ void k_init(const int* __restrict__ batch, int* __restrict__ bucketCnt,
                       int* __restrict__ off, int* __restrict__ rowptr) {
    int i = blockIdx.x * blockDim.x + threadIdx.x;
    if (i >= N_NODES) return;
    if (i < NB) bucketCnt[i] = 0;
    if (i == 0) rowptr[N_NODES] = N_EDGES;
    int b = batch[i];
    if (i == 0) {
        for (int g = 0; g <= b; ++g) off[g] = 0;
    } else {
        int pb = batch[i - 1];
        for (int g = pb + 1; g <= b; ++g) off[g] = i;
    }
    if (i == N_NODES - 1) {
        for (int g = b + 1; g <= N_GRAPHS; ++g) off[g] = N_NODES;
    }
}

// ---------------------------------------------------------------------------
// K1: bucket histogram (LDS-aggregated, well-distributed addresses)
// ---------------------------------------------------------------------------
__global__ __launch_bounds__(256) void k_bhist(const int* __restrict__ dst,
                                               int* __restrict__ bucketCnt) {
    __shared__ int h[NB];
    int t = threadIdx.x;
    for (int b = t; b < NB; b += 256) h[b] = 0;
    __syncthreads();
    int base = blockIdx.x * EB + t;
#pragma unroll
    for (int k = 0; k < EPT; ++k) {
        int e = base + k * 256;
        if (e < N_EDGES) atomicAdd(&h[dst[e] >> 8], 1);
    }
    __syncthreads();
    for (int b = t; b < NB; b += 256) {
        int c = h[b];
        if (c) atomicAdd(&bucketCnt[b], c);
    }
}

// ---------------------------------------------------------------------------
// K2: exclusive scan of bucket counts -> offsets + cursors
// ---------------------------------------------------------------------------
__global__ __launch_bounds__(256) void k_bscan(const int* __restrict__ bucketCnt,
                                               int* __restrict__ bucketOff,
                                               int* __restrict__ bucketCur) {
    __shared__ int sc[256];
    int t = threadIdx.x;
    int v[3];
    int s = 0;
#pragma unroll
    for (int k = 0; k < 3; ++k) {
        int i = t * 3 + k;
        v[k] = (i < NB) ? bucketCnt[i] : 0;
        s += v[k];
    }
    sc[t] = s;
    __syncthreads();
    for (int o = 1; o < 256; o <<= 1) {
        int x = (t >= o) ? sc[t - o] : 0;
        __syncthreads();
        sc[t] += x;
        __syncthreads();
    }
    int run = sc[t] - s;
#pragma unroll
    for (int k = 0; k < 3; ++k) {
        int i = t * 3 + k;
        if (i < NB) { bucketOff[i] = run; bucketCur[i] = run; }
        run += v[k];
    }
    if (t == 0) bucketOff[NB] = N_EDGES;
}

// ---------------------------------------------------------------------------
// K3: bin edges into buckets. key = (localdst << 18) | src
// ---------------------------------------------------------------------------
__global__ __launch_bounds__(256) void k_bin(const int* __restrict__ src,
                                             const int* __restrict__ dst,
                                             int* __restrict__ bucketCur,
                                             unsigned int* __restrict__ binned) {
    __shared__ int h[NB];
    __shared__ int gb[NB];
    int t = threadIdx.x;
    for (int b = t; b < NB; b += 256) h[b] = 0;
    __syncthreads();
    int base = blockIdx.x * EB + t;
    unsigned int key[EPT];
    int rk[EPT], bk[EPT];
#pragma unroll
    for (int k = 0; k < EPT; ++k) {
        int e = base + k * 256;
        if (e < N_EDGES) {
            int d = dst[e];
            int b = d >> 8;
            bk[k] = b;
            key[k] = ((unsigned int)(d & 255) << 18) | (unsigned int)src[e];
            rk[k] = atomicAdd(&h[b], 1);
        } else {
            bk[k] = -1;
        }
    }
    __syncthreads();
    for (int b = t; b < NB; b += 256) {
        int c = h[b];
        gb[b] = c ? atomicAdd(&bucketCur[b], c) : 0;
    }
    __syncthreads();
#pragma unroll
    for (int k = 0; k < EPT; ++k)
        if (bk[k] >= 0) binned[gb[bk[k]] + rk[k]] = key[k];
}

// ---------------------------------------------------------------------------
// K4: per-bucket CSR finalize: rowptr, dinv, xs = x*dinv (fused), csr fill
// ---------------------------------------------------------------------------
__global__ __launch_bounds__(256) void k_csr(const unsigned int* __restrict__ binned,
                                             const int* __restrict__ bucketOff,
                                             const float* __restrict__ x,
                                             int* __restrict__ rowptr,
                                             float* __restrict__ dinv,
                                             float* __restrict__ xs,
                                             int* __restrict__ csr) {
    __shared__ int lcnt[256];
    __shared__ int lpre[256];
    __shared__ int sc[256];
    int b = blockIdx.x, t = threadIdx.x;
    int e0 = bucketOff[b], e1 = bucketOff[b + 1];
    lcnt[t] = 0;
    __syncthreads();
    for (int e = e0 + t; e < e1; e += 256)
        atomicAdd(&lcnt[binned[e] >> 18], 1);
    __syncthreads();
    int v = lcnt[t];
    sc[t] = v;
    __syncthreads();
    for (int o = 1; o < 256; o <<= 1) {
        int x2 = (t >= o) ? sc[t - o] : 0;
        __syncthreads();
        sc[t] += x2;
        __syncthreads();
    }
    int excl = sc[t] - v;
    lpre[t] = excl;
    int gnode = b * BS + t;
    if (gnode < N_NODES) {
        rowptr[gnode] = e0 + excl;
        float dv = rsqrtf((float)v + 1.0f);
        dinv[gnode] = dv;
        xs[gnode * 3 + 0] = x[gnode * 3 + 0] * dv;
        xs[gnode * 3 + 1] = x[gnode * 3 + 1] * dv;
        xs[gnode * 3 + 2] = x[gnode * 3 + 2] * dv;
    }
    lcnt[t] = 0;
    __syncthreads();
    for (int e = e0 + t; e < e1; e += 256) {
        unsigned int key = binned[e];
        int ld = key >> 18;
        int pos = atomicAdd(&lcnt[ld], 1);
        csr[e0 + lpre[ld] + pos] = (int)(key & 0x3FFFFu);
    }
}

// ---------------------------------------------------------------------------
// K5a: layer-1 aggregate(3-wide, pre-scaled xs) + transform(3->32) + bias.
// 8 threads/node. Plain loads (no NT).
// ---------------------------------------------------------------------------
__global__ __launch_bounds__(256) void k_gat3(
        const float* __restrict__ xs, const int* __restrict__ csr,
        const int* __restrict__ rowptr, const float* __restrict__ dinv,
        const float* __restrict__ W, const float* __restrict__ bias,
        float* __restrict__ y) {
    int gid = blockIdx.x * 256 + threadIdx.x;
    int n = gid >> 3, c = gid & 7;
    if (n >= N_NODES) return;
    float z0 = xs[n * 3 + 0], z1 = xs[n * 3 + 1], z2 = xs[n * 3 + 2];
    int e0 = rowptr[n], e1 = rowptr[n + 1];
    for (int e = e0; e < e1; ++e) {
        int s = csr[e];
        z0 += xs[s * 3 + 0];
        z1 += xs[s * 3 + 1];
        z2 += xs[s * 3 + 2];
    }
    float dd = dinv[n];
    z0 *= dd; z1 *= dd; z2 *= dd;
    float4 w0 = ((const float4*)(W + 0 * F))[c];
    float4 w1 = ((const float4*)(W + 1 * F))[c];
    float4 w2 = ((const float4*)(W + 2 * F))[c];
    float4 o  = ((const float4*)bias)[c];
    o.x += z0 * w0.x + z1 * w1.x + z2 * w2.x;
    o.y += z0 * w0.y + z1 * w1.y + z2 * w2.y;
    o.z += z0 * w0.z + z1 * w1.z + z2 * w2.z;
    o.w += z0 * w0.w + z1 * w1.w + z2 * w2.w;
    ((float4*)y)[n * 8 + c] = o;
}

// ---------------------------------------------------------------------------
// K5b: aggregate(32-wide bf16 rows, self from xh) + transform(32->32) + bias.
// 4 threads/node, 16B loads, 2x-unrolled edge loop. Plain loads/stores.
// ---------------------------------------------------------------------------
__global__ __launch_bounds__(256) void k_gat32(
        const unsigned short* __restrict__ xh, const int* __restrict__ csr,
        const int* __restrict__ rowptr, const float* __restrict__ dinv,
        const float* __restrict__ W, const float* __restrict__ bias,
        float* __restrict__ y) {
    __shared__ float Ws[F * F];     // 4 KB
    __shared__ float bs[F];
    __shared__ float Zs[64 * 36];   // 9 KB
    int t = threadIdx.x;
    ((float4*)Ws)[t] = ((const float4*)W)[t];
    if (t < F) bs[t] = bias[t];
    __syncthreads();

    int gid = blockIdx.x * 256 + t;
    int n = gid >> 2, c = gid & 3, ln = t >> 2;
    bool act = (n < N_NODES);
    float acc[8];
    if (act) {
        const uint4* xr = (const uint4*)xh;  // row = 4 x 16B
        // self loop: dd^2 * x[n] = dd * xh[n]
        uint4 us = xr[n * 4 + c];
        acc[0] = bflo(us.x); acc[1] = bfhi(us.x);
        acc[2] = bflo(us.y); acc[3] = bfhi(us.y);
        acc[4] = bflo(us.z); acc[5] = bfhi(us.z);
        acc[6] = bflo(us.w); acc[7] = bfhi(us.w);
        int e0 = rowptr[n], e1 = rowptr[n + 1];
        int e = e0;
        for (; e + 1 < e1; e += 2) {
            int s0 = csr[e], s1 = csr[e + 1];
            uint4 u0 = xr[s0 * 4 + c];
            uint4 u1 = xr[s1 * 4 + c];
            acc[0] += bflo(u0.x); acc[1] += bfhi(u0.x);
            acc[2] += bflo(u0.y); acc[3] += bfhi(u0.y);
            acc[4] += bflo(u0.z); acc[5] += bfhi(u0.z);
            acc[6] += bflo(u0.w); acc[7] += bfhi(u0.w);
            acc[0] += bflo(u1.x); acc[1] += bfhi(u1.x);
            acc[2] += bflo(u1.y); acc[3] += bfhi(u1.y);
            acc[4] += bflo(u1.z); acc[5] += bfhi(u1.z);
            acc[6] += bflo(u1.w); acc[7] += bfhi(u1.w);
        }
        if (e < e1) {
            int s0 = csr[e];
            uint4 u0 = xr[s0 * 4 + c];
            acc[0] += bflo(u0.x); acc[1] += bfhi(u0.x);
            acc[2] += bflo(u0.y); acc[3] += bfhi(u0.y);
            acc[4] += bflo(u0.z); acc[5] += bfhi(u0.z);
            acc[6] += bflo(u0.w); acc[7] += bfhi(u0.w);
        }
        float dd = dinv[n];
#pragma unroll
        for (int j = 0; j < 8; ++j) acc[j] *= dd;
    } else {
#pragma unroll
        for (int j = 0; j < 8; ++j) acc[j] = 0.f;
    }
    *(float4*)&Zs[ln * 36 + c * 8]     = *(float4*)&acc[0];
    *(float4*)&Zs[ln * 36 + c * 8 + 4] = *(float4*)&acc[4];
    __syncthreads();

    if (act) {
        const float* zrow = &Zs[ln * 36];
        float4 o0 = ((const float4*)bs)[c * 2];
        float4 o1 = ((const float4*)bs)[c * 2 + 1];
#pragma unroll
        for (int k = 0; k < F; ++k) {
            float zk = zrow[k];
            float4 w0 = ((const float4*)&Ws[k * F])[c * 2];
            float4 w1 = ((const float4*)&Ws[k * F])[c * 2 + 1];
            o0.x += zk * w0.x; o0.y += zk * w0.y; o0.z += zk * w0.z; o0.w += zk * w0.w;
            o1.x += zk * w1.x; o1.y += zk * w1.y; o1.z += zk * w1.z; o1.w += zk * w1.w;
        }
        ((float4*)y)[n * 8 + c * 2]     = o0;
        ((float4*)y)[n * 8 + c * 2 + 1] = o1;
    }
}

// ---------------------------------------------------------------------------
// K6: GraphNorm, block per graph; single-pass stats (sum/sumsq), normalize
// pass re-reads the ~19KB graph slice L2-hot. In-place capable. Emits fp32
// out + (WXH) bf16 dinv-pre-scaled xh.
// ---------------------------------------------------------------------------
template <bool RES, bool WXH>
__global__ __launch_bounds__(256) void k_gn2(
        const float* agg, const float* res, const int* __restrict__ off,
        const float* __restrict__ gw, const float* __restrict__ gb,
        const float* __restrict__ gms, const float* __restrict__ dinv,
        unsigned short* __restrict__ xh, float* outp) {
    __shared__ float red1[256], red2[256];
    __shared__ float mv_s[F], sc_s[F];
    int g = blockIdx.x;
    int i0 = off[g], i1 = off[g + 1];
    float rc = 1.0f / (float)(i1 - i0);
    int t = threadIdx.x;
    int f = t & 31, r0 = t >> 5;

    float s = 0.f, q = 0.f;
    for (int n = i0 + r0; n < i1; n += 8) {
        float v = agg[n * F + f];
        s += v; q += v * v;
    }
    red1[t] = s; red2[t] = q; __syncthreads();
    if (t < 128) { red1[t] += red1[t + 128]; red2[t] += red2[t + 128]; } __syncthreads();
    if (t < 64)  { red1[t] += red1[t + 64];  red2[t] += red2[t + 64];  } __syncthreads();
    if (t < 32) {
        float sm = (red1[t] + red1[t + 32]) * rc;
        float sq = (red2[t] + red2[t + 32]) * rc;
        float mv = gms[t] * sm;
        float var = sq - mv * (2.f * sm - mv);
        mv_s[t] = mv;
        sc_s[t] = gw[t] * rsqrtf(var + EPSV);
    }
    __syncthreads();

    float w = sc_s[f], mv = mv_s[f], bb = gb[f];
    for (int n = i0 + r0; n < i1; n += 8) {
        float y = (agg[n * F + f] - mv) * w + bb;
        if (RES) y += res[n * F + f];
        y = fmaxf(y, 0.f);
        outp[n * F + f] = y;
        if (WXH) xh[n * F + f] = (unsigned short)f2bf(y * dinv[n]);
    }
}

// ---------------------------------------------------------------------------
// K7: final GraphNorm + residual + ReLU + mean-pool + 32x3 linear
// ---------------------------------------------------------------------------
__global__ __launch_bounds__(256) void k_gnfin(
        const float* __restrict__ agg, const float* __restrict__ res,
        const int* __restrict__ off,
        const float* __restrict__ gw, const float* __restrict__ gb,
        const float* __restrict__ gms,
        const float* __restrict__ lin_w, const float* __restrict__ lin_b,
        float* __restrict__ outp) {
    __shared__ float red1[256], red2[256];
    __shared__ float mv_s[F], sc_s[F], pooled_s[F];
    int g = blockIdx.x;
    int i0 = off[g], i1 = off[g + 1];
    float cnt = (float)(i1 - i0);
    float rc = 1.0f / cnt;
    int t = threadIdx.x;
    int f = t & 31, r0 = t >> 5;

    float s = 0.f, q = 0.f;
    for (int n = i0 + r0; n < i1; n += 8) {
        float v = agg[n * F + f];
        s += v; q += v * v;
    }
    red1[t] = s; red2[t] = q; __syncthreads();
    if (t < 128) { red1[t] += red1[t + 128]; red2[t] += red2[t + 128]; } __syncthreads();
    if (t < 64)  { red1[t] += red1[t + 64];  red2[t] += red2[t + 64];  } __syncthreads();
    if (t < 32) {
        float sm = (red1[t] + red1[t + 32]) * rc;
        float sq = (red2[t] + red2[t + 32]) * rc;
        float mv = gms[t] * sm;
        float var = sq - mv * (2.f * sm - mv);
        mv_s[t] = mv;
        sc_s[t] = gw[t] * rsqrtf(var + EPSV);
    }
    __syncthreads();

    float w = sc_s[f], mv = mv_s[f], bb = gb[f];
    float ps = 0.f;
    for (int n = i0 + r0; n < i1; n += 8) {
        float yv = (agg[n * F + f] - mv) * w + bb + res[n * F + f];
        ps += fmaxf(yv, 0.f);
    }
    __syncthreads();
    red1[t] = ps; __syncthreads();
    if (t < 128) red1[t] += red1[t + 128]; __syncthreads();
    if (t < 64)  red1[t] += red1[t + 64];  __syncthreads();
    if (t < 32) { red1[t] += red1[t + 32]; pooled_s[t] = red1[t] * rc; }
    __syncthreads();
    if (t < 3) {
        float o = lin_b[t];
#pragma unroll
        for (int f2 = 0; f2 < F; ++f2) o += pooled_s[f2] * lin_w[f2 * 3 + t];
        outp[g * 3 + t] = o;
    }
}

// ---------------------------------------------------------------------------
extern "C" void kernel_launch(void* const* d_in, const int* in_sizes, int n_in,
                              void* d_out, int out_size, void* d_ws, size_t ws_size,
                              hipStream_t stream) {
    const float* x      = (const float*)d_in[0];
    const int*   ei     = (const int*)d_in[1];
    const int*   batch  = (const int*)d_in[2];
    const float* W1     = (const float*)d_in[3];
    const float* b1     = (const float*)d_in[4];
    const float* gn1w   = (const float*)d_in[5];
    const float* gn1b   = (const float*)d_in[6];
    const float* gn1ms  = (const float*)d_in[7];
    const float* W2     = (const float*)d_in[8];
    const float* b2     = (const float*)d_in[9];
    const float* gn2w   = (const float*)d_in[10];
    const float* gn2b   = (const float*)d_in[11];
    const float* gn2ms  = (const float*)d_in[12];
    const float* W3     = (const float*)d_in[13];
    const float* b3     = (const float*)d_in[14];
    const float* gn3w   = (const float*)d_in[15];
    const float* gn3b   = (const float*)d_in[16];
    const float* gn3ms  = (const float*)d_in[17];
    const float* lin_w  = (const float*)d_in[18];
    const float* lin_b  = (const float*)d_in[19];
    float* out = (float*)d_out;

    const int* srcp = ei;
    const int* dstp = ei + N_EDGES;

    char* ws = (char*)d_ws;
    size_t p = 0;
    auto alloc = [&](size_t bytes) {
        size_t r = p; p += (bytes + 511) & ~(size_t)511; return r;
    };
    int*   off       = (int*)  (ws + alloc(sizeof(int) * (N_GRAPHS + 1)));
    int*   bucketCnt = (int*)  (ws + alloc(sizeof(int) * NB));
    int*   bucketOff = (int*)  (ws + alloc(sizeof(int) * (NB + 1)));
    int*   bucketCur = (int*)  (ws + alloc(sizeof(int) * NB));
    int*   rowptr    = (int*)  (ws + alloc(sizeof(int) * (N_NODES + 1)));
    float* dinv      = (float*)(ws + alloc(sizeof(float) * N_NODES));
    float* xs        = (float*)(ws + alloc(sizeof(float) * N_NODES * 3));
    unsigned int* binned = (unsigned int*)(ws + alloc(sizeof(unsigned int) * N_EDGES));
    int*   csr       = (int*)  (ws + alloc(sizeof(int) * N_EDGES));
    float* A         = (float*)(ws + alloc(sizeof(float) * N_NODES * F));
    float* B         = (float*)(ws + alloc(sizeof(float) * N_NODES * F));
    // xh aliases binned (dead after k_csr); both exactly 9.6 MB.
    unsigned short* xh = (unsigned short*)binned;
    (void)ws_size; (void)n_in; (void)in_sizes; (void)out_size;

    const int TB = 256;
    dim3 blk(TB);
    int ngrid  = (N_NODES + TB - 1) / TB;
    int ggrid8 = (N_NODES * 8 + TB - 1) / TB;
    int ggrid4 = (N_NODES * 4 + TB - 1) / TB;

    // CSR build via bucketed counting sort (+ dinv, xs fused into k_csr)
    k_init <<<ngrid, blk, 0, stream>>>(batch, bucketCnt, off, rowptr);
    k_bhist<<<NEB, blk, 0, stream>>>(dstp, bucketCnt);
    k_bscan<<<1, blk, 0, stream>>>(bucketCnt, bucketOff, bucketCur);
    k_bin  <<<NEB, blk, 0, stream>>>(srcp, dstp, bucketCur, binned);
    k_csr  <<<NB, blk, 0, stream>>>(binned, bucketOff, x, rowptr, dinv, xs, csr);

    // layer 1: gather+transform -> A ; GN in-place -> x1=A (+ bf16 xh)
    k_gat3 <<<ggrid8, blk, 0, stream>>>(xs, csr, rowptr, dinv, W1, b1, A);
    k_gn2<false, true><<<N_GRAPHS, blk, 0, stream>>>(
        A, nullptr, off, gn1w, gn1b, gn1ms, dinv, xh, A);

    // layer 2: gather(xh)+transform -> B ; GN + res(A) in-place -> x2=B (+ xh)
    k_gat32<<<ggrid4, blk, 0, stream>>>(xh, csr, rowptr, dinv, W2, b2, B);
    k_gn2<true, true><<<N_GRAPHS, blk, 0, stream>>>(
        B, A, off, gn2w, gn2b, gn2ms, dinv, xh, B);

    // layer 3: gather(xh)+transform -> A ; GN + res(B) + pool + linear -> out
    k_gat32<<<ggrid4, blk, 0, stream>>>(xh, csr, rowptr, dinv, W3, b3, A);
    k_gnfin<<<N_GRAPHS, blk, 0, stream>>>(A, B, off, gn3w, gn3b, gn3ms,
                                          lin_w, lin_b, out);
}

// Round 10
// 338.492 us; speedup vs baseline: 3.3332x; 1.0429x over previous
//
#include <hip/hip_runtime.h>

#define N_NODES 150000
#define N_EDGES 2400000
#define N_GRAPHS 1024
#define F 32
#define EPSV 1e-5f

#define BS 256                                   // nodes per dst-bucket
#define NB ((N_NODES + BS - 1) / BS)             // 586 buckets
#define EB 8192                                  // edges per binning block
#define NEB ((N_EDGES + EB - 1) / EB)            // 293 blocks
#define EPT (EB / 256)                           // 32 edges per thread

// bf16 helpers (RTN-even encode; decode via shift/mask)
__device__ __forceinline__ float bflo(unsigned int u) {
    union { unsigned int i; float f; } v; v.i = u << 16; return v.f;
}
__device__ __forceinline__ float bfhi(unsigned int u) {
    union { unsigned int i; float f; } v; v.i = u & 0xffff0000u; return v.f;
}
__device__ __forceinline__ unsigned int f2bf(float f) {
    union { float f; unsigned int i; } v; v.f = f;
    unsigned int r = v.i + 0x7fff + ((v.i >> 16) & 1);
    return r >> 16;
}

// ---------------------------------------------------------------------------
// K0: graph offsets from sorted batch; zero bucket histogram
// ---------------------------------------------------------------------------
__global__ void k_init(const int* __restrict__ batch, int* __restrict__ bucketCnt,
                       int* __restrict__ off, int* __restrict__ rowptr) {
    int i = blockIdx.x * blockDim.x + threadIdx.x;
    if (i >= N_NODES) return;
    if (i < NB) bucketCnt[i] = 0;
    if (i == 0) rowptr[N_NODES] = N_EDGES;
    int b = batch[i];
    if (i == 0) {
        for (int g = 0; g <= b; ++g) off[g] = 0;
    } else {
        int pb = batch[i - 1];
        for (int g = pb + 1; g <= b; ++g) off[g] = i;
    }
    if (i == N_NODES - 1) {
        for (int g = b + 1; g <= N_GRAPHS; ++g) off[g] = N_NODES;
    }
}

// ---------------------------------------------------------------------------
// K1: bucket histogram (LDS-aggregated, well-distributed addresses)
// ---------------------------------------------------------------------------
__global__ __launch_bounds__(256) void k_bhist(const int* __restrict__ dst,
                                               int* __restrict__ bucketCnt) {
    __shared__ int h[NB];
    int t = threadIdx.x;
    for (int b = t; b < NB; b += 256) h[b] = 0;
    __syncthreads();
    int base = blockIdx.x * EB + t;
#pragma unroll
    for (int k = 0; k < EPT; ++k) {
        int e = base + k * 256;
        if (e < N_EDGES) atomicAdd(&h[dst[e] >> 8], 1);
    }
    __syncthreads();
    for (int b = t; b < NB; b += 256) {
        int c = h[b];
        if (c) atomicAdd(&bucketCnt[b], c);
    }
}

// ---------------------------------------------------------------------------
// K2: exclusive scan of bucket counts -> offsets + cursors
// ---------------------------------------------------------------------------
__global__ __launch_bounds__(256) void k_bscan(const int* __restrict__ bucketCnt,
                                               int* __restrict__ bucketOff,
                                               int* __restrict__ bucketCur) {
    __shared__ int sc[256];
    int t = threadIdx.x;
    int v[3];
    int s = 0;
#pragma unroll
    for (int k = 0; k < 3; ++k) {
        int i = t * 3 + k;
        v[k] = (i < NB) ? bucketCnt[i] : 0;
        s += v[k];
    }
    sc[t] = s;
    __syncthreads();
    for (int o = 1; o < 256; o <<= 1) {
        int x = (t >= o) ? sc[t - o] : 0;
        __syncthreads();
        sc[t] += x;
        __syncthreads();
    }
    int run = sc[t] - s;
#pragma unroll
    for (int k = 0; k < 3; ++k) {
        int i = t * 3 + k;
        if (i < NB) { bucketOff[i] = run; bucketCur[i] = run; }
        run += v[k];
    }
    if (t == 0) bucketOff[NB] = N_EDGES;
}

// ---------------------------------------------------------------------------
// K3: bin edges into buckets. key = (localdst << 18) | src.
// EB=8192 -> ~14-key runs per (block,bucket): halves partial-line write amp
// vs EB=4096. Per-edge state packed as (rank<<10)|bucket to limit VGPRs.
// ---------------------------------------------------------------------------
__global__ __launch_bounds__(256) void k_bin(const int* __restrict__ src,
                                             const int* __restrict__ dst,
                                             int* __restrict__ bucketCur,
                                             unsigned int* __restrict__ binned) {
    __shared__ int h[NB];
    __shared__ int gb[NB];
    int t = threadIdx.x;
    for (int b = t; b < NB; b += 256) h[b] = 0;
    __syncthreads();
    int base = blockIdx.x * EB + t;
    unsigned int key[EPT];
    unsigned int pk[EPT];               // (rank<<10) | bucket ; 0xFFFFFFFF = inactive
#pragma unroll
    for (int k = 0; k < EPT; ++k) {
        int e = base + k * 256;
        if (e < N_EDGES) {
            int d = dst[e];
            int b = d >> 8;
            key[k] = ((unsigned int)(d & 255) << 18) | (unsigned int)src[e];
            unsigned int rk = (unsigned int)atomicAdd(&h[b], 1);
            pk[k] = (rk << 10) | (unsigned int)b;
        } else {
            pk[k] = 0xFFFFFFFFu;
        }
    }
    __syncthreads();
    for (int b = t; b < NB; b += 256) {
        int c = h[b];
        gb[b] = c ? atomicAdd(&bucketCur[b], c) : 0;
    }
    __syncthreads();
#pragma unroll
    for (int k = 0; k < EPT; ++k) {
        if (pk[k] != 0xFFFFFFFFu) {
            unsigned int b = pk[k] & 1023u;
            unsigned int rk = pk[k] >> 10;
            binned[gb[b] + rk] = key[k];
        }
    }
}

// ---------------------------------------------------------------------------
// K4: per-bucket CSR finalize: rowptr, dinv, xs = x*dinv (fused), csr fill
// ---------------------------------------------------------------------------
__global__ __launch_bounds__(256) void k_csr(const unsigned int* __restrict__ binned,
                                             const int* __restrict__ bucketOff,
                                             const float* __restrict__ x,
                                             int* __restrict__ rowptr,
                                             float* __restrict__ dinv,
                                             float* __restrict__ xs,
                                             int* __restrict__ csr) {
    __shared__ int lcnt[256];
    __shared__ int lpre[256];
    __shared__ int sc[256];
    int b = blockIdx.x, t = threadIdx.x;
    int e0 = bucketOff[b], e1 = bucketOff[b + 1];
    lcnt[t] = 0;
    __syncthreads();
    for (int e = e0 + t; e < e1; e += 256)
        atomicAdd(&lcnt[binned[e] >> 18], 1);
    __syncthreads();
    int v = lcnt[t];
    sc[t] = v;
    __syncthreads();
    for (int o = 1; o < 256; o <<= 1) {
        int x2 = (t >= o) ? sc[t - o] : 0;
        __syncthreads();
        sc[t] += x2;
        __syncthreads();
    }
    int excl = sc[t] - v;
    lpre[t] = excl;
    int gnode = b * BS + t;
    if (gnode < N_NODES) {
        rowptr[gnode] = e0 + excl;
        float dv = rsqrtf((float)v + 1.0f);
        dinv[gnode] = dv;
        xs[gnode * 3 + 0] = x[gnode * 3 + 0] * dv;
        xs[gnode * 3 + 1] = x[gnode * 3 + 1] * dv;
        xs[gnode * 3 + 2] = x[gnode * 3 + 2] * dv;
    }
    lcnt[t] = 0;
    __syncthreads();
    for (int e = e0 + t; e < e1; e += 256) {
        unsigned int key = binned[e];
        int ld = key >> 18;
        int pos = atomicAdd(&lcnt[ld], 1);
        csr[e0 + lpre[ld] + pos] = (int)(key & 0x3FFFFu);
    }
}

// ---------------------------------------------------------------------------
// K5a: layer-1 aggregate(3-wide, pre-scaled xs) + transform(3->32) + bias.
// 8 threads/node.
// ---------------------------------------------------------------------------
__global__ __launch_bounds__(256) void k_gat3(
        const float* __restrict__ xs, const int* __restrict__ csr,
        const int* __restrict__ rowptr, const float* __restrict__ dinv,
        const float* __restrict__ W, const float* __restrict__ bias,
        float* __restrict__ y) {
    int gid = blockIdx.x * 256 + threadIdx.x;
    int n = gid >> 3, c = gid & 7;
    if (n >= N_NODES) return;
    float z0 = xs[n * 3 + 0], z1 = xs[n * 3 + 1], z2 = xs[n * 3 + 2];
    int e0 = rowptr[n], e1 = rowptr[n + 1];
    for (int e = e0; e < e1; ++e) {
        int s = csr[e];
        z0 += xs[s * 3 + 0];
        z1 += xs[s * 3 + 1];
        z2 += xs[s * 3 + 2];
    }
    float dd = dinv[n];
    z0 *= dd; z1 *= dd; z2 *= dd;
    float4 w0 = ((const float4*)(W + 0 * F))[c];
    float4 w1 = ((const float4*)(W + 1 * F))[c];
    float4 w2 = ((const float4*)(W + 2 * F))[c];
    float4 o  = ((const float4*)bias)[c];
    o.x += z0 * w0.x + z1 * w1.x + z2 * w2.x;
    o.y += z0 * w0.y + z1 * w1.y + z2 * w2.y;
    o.z += z0 * w0.z + z1 * w1.z + z2 * w2.z;
    o.w += z0 * w0.w + z1 * w1.w + z2 * w2.w;
    ((float4*)y)[n * 8 + c] = o;
}

// ---------------------------------------------------------------------------
// K5b: aggregate(32-wide bf16 rows, self from xh) + transform(32->32) + bias.
// 4 threads/node, 16B loads, 4x-unrolled edge loop (4 rows in flight).
// ---------------------------------------------------------------------------
__global__ __launch_bounds__(256) void k_gat32(
        const unsigned short* __restrict__ xh, const int* __restrict__ csr,
        const int* __restrict__ rowptr, const float* __restrict__ dinv,
        const float* __restrict__ W, const float* __restrict__ bias,
        float* __restrict__ y) {
    __shared__ float Ws[F * F];     // 4 KB
    __shared__ float bs[F];
    __shared__ float Zs[64 * 36];   // 9 KB
    int t = threadIdx.x;
    ((float4*)Ws)[t] = ((const float4*)W)[t];
    if (t < F) bs[t] = bias[t];
    __syncthreads();

    int gid = blockIdx.x * 256 + t;
    int n = gid >> 2, c = gid & 3, ln = t >> 2;
    bool act = (n < N_NODES);
    float acc[8];
    if (act) {
        const uint4* xr = (const uint4*)xh;  // row = 4 x 16B
        // self loop: dd^2 * x[n] = dd * xh[n]
        uint4 us = xr[n * 4 + c];
        acc[0] = bflo(us.x); acc[1] = bfhi(us.x);
        acc[2] = bflo(us.y); acc[3] = bfhi(us.y);
        acc[4] = bflo(us.z); acc[5] = bfhi(us.z);
        acc[6] = bflo(us.w); acc[7] = bfhi(us.w);
        int e0 = rowptr[n], e1 = rowptr[n + 1];
        int e = e0;
        for (; e + 3 < e1; e += 4) {
            int s0 = csr[e], s1 = csr[e + 1], s2 = csr[e + 2], s3 = csr[e + 3];
            uint4 u0 = xr[s0 * 4 + c];
            uint4 u1 = xr[s1 * 4 + c];
            uint4 u2 = xr[s2 * 4 + c];
            uint4 u3 = xr[s3 * 4 + c];
            acc[0] += bflo(u0.x); acc[1] += bfhi(u0.x);
            acc[2] += bflo(u0.y); acc[3] += bfhi(u0.y);
            acc[4] += bflo(u0.z); acc[5] += bfhi(u0.z);
            acc[6] += bflo(u0.w); acc[7] += bfhi(u0.w);
            acc[0] += bflo(u1.x); acc[1] += bfhi(u1.x);
            acc[2] += bflo(u1.y); acc[3] += bfhi(u1.y);
            acc[4] += bflo(u1.z); acc[5] += bfhi(u1.z);
            acc[6] += bflo(u1.w); acc[7] += bfhi(u1.w);
            acc[0] += bflo(u2.x); acc[1] += bfhi(u2.x);
            acc[2] += bflo(u2.y); acc[3] += bfhi(u2.y);
            acc[4] += bflo(u2.z); acc[5] += bfhi(u2.z);
            acc[6] += bflo(u2.w); acc[7] += bfhi(u2.w);
            acc[0] += bflo(u3.x); acc[1] += bfhi(u3.x);
            acc[2] += bflo(u3.y); acc[3] += bfhi(u3.y);
            acc[4] += bflo(u3.z); acc[5] += bfhi(u3.z);
            acc[6] += bflo(u3.w); acc[7] += bfhi(u3.w);
        }
        for (; e < e1; ++e) {
            int s0 = csr[e];
            uint4 u0 = xr[s0 * 4 + c];
            acc[0] += bflo(u0.x); acc[1] += bfhi(u0.x);
            acc[2] += bflo(u0.y); acc[3] += bfhi(u0.y);
            acc[4] += bflo(u0.z); acc[5] += bfhi(u0.z);
            acc[6] += bflo(u0.w); acc[7] += bfhi(u0.w);
        }
        float dd = dinv[n];
#pragma unroll
        for (int j = 0; j < 8; ++j) acc[j] *= dd;
    } else {
#pragma unroll
        for (int j = 0; j < 8; ++j) acc[j] = 0.f;
    }
    *(float4*)&Zs[ln * 36 + c * 8]     = *(float4*)&acc[0];
    *(float4*)&Zs[ln * 36 + c * 8 + 4] = *(float4*)&acc[4];
    __syncthreads();

    if (act) {
        const float* zrow = &Zs[ln * 36];
        float4 o0 = ((const float4*)bs)[c * 2];
        float4 o1 = ((const float4*)bs)[c * 2 + 1];
#pragma unroll
        for (int k = 0; k < F; ++k) {
            float zk = zrow[k];
            float4 w0 = ((const float4*)&Ws[k * F])[c * 2];
            float4 w1 = ((const float4*)&Ws[k * F])[c * 2 + 1];
            o0.x += zk * w0.x; o0.y += zk * w0.y; o0.z += zk * w0.z; o0.w += zk * w0.w;
            o1.x += zk * w1.x; o1.y += zk * w1.y; o1.z += zk * w1.z; o1.w += zk * w1.w;
        }
        ((float4*)y)[n * 8 + c * 2]     = o0;
        ((float4*)y)[n * 8 + c * 2 + 1] = o1;
    }
}

// ---------------------------------------------------------------------------
// K6: GraphNorm, block per graph; single-pass stats (sum/sumsq), normalize
// pass re-reads the ~19KB graph slice L2-hot. In-place capable. Emits fp32
// out + (WXH) bf16 dinv-pre-scaled xh.
// ---------------------------------------------------------------------------
template <bool RES, bool WXH>
__global__ __launch_bounds__(256) void k_gn2(
        const float* agg, const float* res, const int* __restrict__ off,
        const float* __restrict__ gw, const float* __restrict__ gb,
        const float* __restrict__ gms, const float* __restrict__ dinv,
        unsigned short* __restrict__ xh, float* outp) {
    __shared__ float red1[256], red2[256];
    __shared__ float mv_s[F], sc_s[F];
    int g = blockIdx.x;
    int i0 = off[g], i1 = off[g + 1];
    float rc = 1.0f / (float)(i1 - i0);
    int t = threadIdx.x;
    int f = t & 31, r0 = t >> 5;

    float s = 0.f, q = 0.f;
    for (int n = i0 + r0; n < i1; n += 8) {
        float v = agg[n * F + f];
        s += v; q += v * v;
    }
    red1[t] = s; red2[t] = q; __syncthreads();
    if (t < 128) { red1[t] += red1[t + 128]; red2[t] += red2[t + 128]; } __syncthreads();
    if (t < 64)  { red1[t] += red1[t + 64];  red2[t] += red2[t + 64];  } __syncthreads();
    if (t < 32) {
        float sm = (red1[t] + red1[t + 32]) * rc;
        float sq = (red2[t] + red2[t + 32]) * rc;
        float mv = gms[t] * sm;
        float var = sq - mv * (2.f * sm - mv);
        mv_s[t] = mv;
        sc_s[t] = gw[t] * rsqrtf(var + EPSV);
    }
    __syncthreads();

    float w = sc_s[f], mv = mv_s[f], bb = gb[f];
    for (int n = i0 + r0; n < i1; n += 8) {
        float y = (agg[n * F + f] - mv) * w + bb;
        if (RES) y += res[n * F + f];
        y = fmaxf(y, 0.f);
        outp[n * F + f] = y;
        if (WXH) xh[n * F + f] = (unsigned short)f2bf(y * dinv[n]);
    }
}

// ---------------------------------------------------------------------------
// K7: final GraphNorm + residual + ReLU + mean-pool + 32x3 linear
// ---------------------------------------------------------------------------
__global__ __launch_bounds__(256) void k_gnfin(
        const float* __restrict__ agg, const float* __restrict__ res,
        const int* __restrict__ off,
        const float* __restrict__ gw, const float* __restrict__ gb,
        const float* __restrict__ gms,
        const float* __restrict__ lin_w, const float* __restrict__ lin_b,
        float* __restrict__ outp) {
    __shared__ float red1[256], red2[256];
    __shared__ float mv_s[F], sc_s[F], pooled_s[F];
    int g = blockIdx.x;
    int i0 = off[g], i1 = off[g + 1];
    float cnt = (float)(i1 - i0);
    float rc = 1.0f / cnt;
    int t = threadIdx.x;
    int f = t & 31, r0 = t >> 5;

    float s = 0.f, q = 0.f;
    for (int n = i0 + r0; n < i1; n += 8) {
        float v = agg[n * F + f];
        s += v; q += v * v;
    }
    red1[t] = s; red2[t] = q; __syncthreads();
    if (t < 128) { red1[t] += red1[t + 128]; red2[t] += red2[t + 128]; } __syncthreads();
    if (t < 64)  { red1[t] += red1[t + 64];  red2[t] += red2[t + 64];  } __syncthreads();
    if (t < 32) {
        float sm = (red1[t] + red1[t + 32]) * rc;
        float sq = (red2[t] + red2[t + 32]) * rc;
        float mv = gms[t] * sm;
        float var = sq - mv * (2.f * sm - mv);
        mv_s[t] = mv;
        sc_s[t] = gw[t] * rsqrtf(var + EPSV);
    }
    __syncthreads();

    float w = sc_s[f], mv = mv_s[f], bb = gb[f];
    float ps = 0.f;
    for (int n = i0 + r0; n < i1; n += 8) {
        float yv = (agg[n * F + f] - mv) * w + bb + res[n * F + f];
        ps += fmaxf(yv, 0.f);
    }
    __syncthreads();
    red1[t] = ps; __syncthreads();
    if (t < 128) red1[t] += red1[t + 128]; __syncthreads();
    if (t < 64)  red1[t] += red1[t + 64];  __syncthreads();
    if (t < 32) { red1[t] += red1[t + 32]; pooled_s[t] = red1[t] * rc; }
    __syncthreads();
    if (t < 3) {
        float o = lin_b[t];
#pragma unroll
        for (int f2 = 0; f2 < F; ++f2) o += pooled_s[f2] * lin_w[f2 * 3 + t];
        outp[g * 3 + t] = o;
    }
}

// ---------------------------------------------------------------------------
extern "C" void kernel_launch(void* const* d_in, const int* in_sizes, int n_in,
                              void* d_out, int out_size, void* d_ws, size_t ws_size,
                              hipStream_t stream) {
    const float* x      = (const float*)d_in[0];
    const int*   ei     = (const int*)d_in[1];
    const int*   batch  = (const int*)d_in[2];
    const float* W1     = (const float*)d_in[3];
    const float* b1     = (const float*)d_in[4];
    const float* gn1w   = (const float*)d_in[5];
    const float* gn1b   = (const float*)d_in[6];
    const float* gn1ms  = (const float*)d_in[7];
    const float* W2     = (const float*)d_in[8];
    const float* b2     = (const float*)d_in[9];
    const float* gn2w   = (const float*)d_in[10];
    const float* gn2b   = (const float*)d_in[11];
    const float* gn2ms  = (const float*)d_in[12];
    const float* W3     = (const float*)d_in[13];
    const float* b3     = (const float*)d_in[14];
    const float* gn3w   = (const float*)d_in[15];
    const float* gn3b   = (const float*)d_in[16];
    const float* gn3ms  = (const float*)d_in[17];
    const float* lin_w  = (const float*)d_in[18];
    const float* lin_b  = (const float*)d_in[19];
    float* out = (float*)d_out;

    const int* srcp = ei;
    const int* dstp = ei + N_EDGES;

    char* ws = (char*)d_ws;
    size_t p = 0;
    auto alloc = [&](size_t bytes) {
        size_t r = p; p += (bytes + 511) & ~(size_t)511; return r;
    };
    int*   off       = (int*)  (ws + alloc(sizeof(int) * (N_GRAPHS + 1)));
    int*   bucketCnt = (int*)  (ws + alloc(sizeof(int) * NB));
    int*   bucketOff = (int*)  (ws + alloc(sizeof(int) * (NB + 1)));
    int*   bucketCur = (int*)  (ws + alloc(sizeof(int) * NB));
    int*   rowptr    = (int*)  (ws + alloc(sizeof(int) * (N_NODES + 1)));
    float* dinv      = (float*)(ws + alloc(sizeof(float) * N_NODES));
    float* xs        = (float*)(ws + alloc(sizeof(float) * N_NODES * 3));
    unsigned int* binned = (unsigned int*)(ws + alloc(sizeof(unsigned int) * N_EDGES));
    int*   csr       = (int*)  (ws + alloc(sizeof(int) * N_EDGES));
    float* A         = (float*)(ws + alloc(sizeof(float) * N_NODES * F));
    float* B         = (float*)(ws + alloc(sizeof(float) * N_NODES * F));
    // xh aliases binned (dead after k_csr); both exactly 9.6 MB.
    unsigned short* xh = (unsigned short*)binned;
    (void)ws_size; (void)n_in; (void)in_sizes; (void)out_size;

    const int TB = 256;
    dim3 blk(TB);
    int ngrid  = (N_NODES + TB - 1) / TB;
    int ggrid8 = (N_NODES * 8 + TB - 1) / TB;
    int ggrid4 = (N_NODES * 4 + TB - 1) / TB;

    // CSR build via bucketed counting sort (+ dinv, xs fused into k_csr)
    k_init <<<ngrid, blk, 0, stream>>>(batch, bucketCnt, off, rowptr);
    k_bhist<<<NEB, blk, 0, stream>>>(dstp, bucketCnt);
    k_bscan<<<1, blk, 0, stream>>>(bucketCnt, bucketOff, bucketCur);
    k_bin  <<<NEB, blk, 0, stream>>>(srcp, dstp, bucketCur, binned);
    k_csr  <<<NB, blk, 0, stream>>>(binned, bucketOff, x, rowptr, dinv, xs, csr);

    // layer 1: gather+transform -> A ; GN in-place -> x1=A (+ bf16 xh)
    k_gat3 <<<ggrid8, blk, 0, stream>>>(xs, csr, rowptr, dinv, W1, b1, A);
    k_gn2<false, true><<<N_GRAPHS, blk, 0, stream>>>(
        A, nullptr, off, gn1w, gn1b, gn1ms, dinv, xh, A);

    // layer 2: gather(xh)+transform -> B ; GN + res(A) in-place -> x2=B (+ xh)
    k_gat32<<<ggrid4, blk, 0, stream>>>(xh, csr, rowptr, dinv, W2, b2, B);
    k_gn2<true, true><<<N_GRAPHS, blk, 0, stream>>>(
        B, A, off, gn2w, gn2b, gn2ms, dinv, xh, B);

    // layer 3: gather(xh)+transform -> A ; GN + res(B) + pool + linear -> out
    k_gat32<<<ggrid4, blk, 0, stream>>>(xh, csr, rowptr, dinv, W3, b3, A);
    k_gnfin<<<N_GRAPHS, blk, 0, stream>>>(A, B, off, gn3w, gn3b, gn3ms,
                                          lin_w, lin_b, out);
}

// Round 11
// 332.742 us; speedup vs baseline: 3.3908x; 1.0173x over previous
//
#include <hip/hip_runtime.h>

#define N_NODES 150000
#define N_EDGES 2400000
#define N_GRAPHS 1024
#define F 32
#define EPSV 1e-5f

#define BS 256                                   // nodes per dst-bucket
#define NB ((N_NODES + BS - 1) / BS)             // 586 buckets
#define EB 8192                                  // edges per binning block
#define NEB ((N_EDGES + EB - 1) / EB)            // 293 blocks
#define EPT (EB / 256)                           // 32 edges per thread

// bf16 helpers (RTN-even encode; decode via shift/mask)
__device__ __forceinline__ float bflo(unsigned int u) {
    union { unsigned int i; float f; } v; v.i = u << 16; return v.f;
}
__device__ __forceinline__ float bfhi(unsigned int u) {
    union { unsigned int i; float f; } v; v.i = u & 0xffff0000u; return v.f;
}
__device__ __forceinline__ unsigned int f2bf(float f) {
    union { float f; unsigned int i; } v; v.f = f;
    unsigned int r = v.i + 0x7fff + ((v.i >> 16) & 1);
    return r >> 16;
}

// ---------------------------------------------------------------------------
// K0: graph offsets from sorted batch; zero bucket histogram
// ---------------------------------------------------------------------------
__global__ void k_init(const int* __restrict__ batch, int* __restrict__ bucketCnt,
                       int* __restrict__ off, int* __restrict__ rowptr) {
    int i = blockIdx.x * blockDim.x + threadIdx.x;
    if (i >= N_NODES) return;
    if (i < NB) bucketCnt[i] = 0;
    if (i == 0) rowptr[N_NODES] = N_EDGES;
    int b = batch[i];
    if (i == 0) {
        for (int g = 0; g <= b; ++g) off[g] = 0;
    } else {
        int pb = batch[i - 1];
        for (int g = pb + 1; g <= b; ++g) off[g] = i;
    }
    if (i == N_NODES - 1) {
        for (int g = b + 1; g <= N_GRAPHS; ++g) off[g] = N_NODES;
    }
}

// ---------------------------------------------------------------------------
// K1: bucket histogram (LDS-aggregated)
// ---------------------------------------------------------------------------
__global__ __launch_bounds__(256) void k_bhist(const int* __restrict__ dst,
                                               int* __restrict__ bucketCnt) {
    __shared__ int h[NB];
    int t = threadIdx.x;
    for (int b = t; b < NB; b += 256) h[b] = 0;
    __syncthreads();
    int base = blockIdx.x * EB + t;
#pragma unroll
    for (int k = 0; k < EPT; ++k) {
        int e = base + k * 256;
        if (e < N_EDGES) atomicAdd(&h[dst[e] >> 8], 1);
    }
    __syncthreads();
    for (int b = t; b < NB; b += 256) {
        int c = h[b];
        if (c) atomicAdd(&bucketCnt[b], c);
    }
}

// ---------------------------------------------------------------------------
// K2: exclusive scan of bucket counts -> offsets + cursors
// ---------------------------------------------------------------------------
__global__ __launch_bounds__(256) void k_bscan(const int* __restrict__ bucketCnt,
                                               int* __restrict__ bucketOff,
                                               int* __restrict__ bucketCur) {
    __shared__ int sc[256];
    int t = threadIdx.x;
    int v[3];
    int s = 0;
#pragma unroll
    for (int k = 0; k < 3; ++k) {
        int i = t * 3 + k;
        v[k] = (i < NB) ? bucketCnt[i] : 0;
        s += v[k];
    }
    sc[t] = s;
    __syncthreads();
    for (int o = 1; o < 256; o <<= 1) {
        int x = (t >= o) ? sc[t - o] : 0;
        __syncthreads();
        sc[t] += x;
        __syncthreads();
    }
    int run = sc[t] - s;
#pragma unroll
    for (int k = 0; k < 3; ++k) {
        int i = t * 3 + k;
        if (i < NB) { bucketOff[i] = run; bucketCur[i] = run; }
        run += v[k];
    }
    if (t == 0) bucketOff[NB] = N_EDGES;
}

// ---------------------------------------------------------------------------
// K3: bin edges into buckets. key = (localdst << 18) | src. EB=8192.
// ---------------------------------------------------------------------------
__global__ __launch_bounds__(256) void k_bin(const int* __restrict__ src,
                                             const int* __restrict__ dst,
                                             int* __restrict__ bucketCur,
                                             unsigned int* __restrict__ binned) {
    __shared__ int h[NB];
    __shared__ int gb[NB];
    int t = threadIdx.x;
    for (int b = t; b < NB; b += 256) h[b] = 0;
    __syncthreads();
    int base = blockIdx.x * EB + t;
    unsigned int key[EPT];
    unsigned int pk[EPT];               // (rank<<10) | bucket ; 0xFFFFFFFF = inactive
#pragma unroll
    for (int k = 0; k < EPT; ++k) {
        int e = base + k * 256;
        if (e < N_EDGES) {
            int d = dst[e];
            int b = d >> 8;
            key[k] = ((unsigned int)(d & 255) << 18) | (unsigned int)src[e];
            unsigned int rk = (unsigned int)atomicAdd(&h[b], 1);
            pk[k] = (rk << 10) | (unsigned int)b;
        } else {
            pk[k] = 0xFFFFFFFFu;
        }
    }
    __syncthreads();
    for (int b = t; b < NB; b += 256) {
        int c = h[b];
        gb[b] = c ? atomicAdd(&bucketCur[b], c) : 0;
    }
    __syncthreads();
#pragma unroll
    for (int k = 0; k < EPT; ++k) {
        if (pk[k] != 0xFFFFFFFFu) {
            unsigned int b = pk[k] & 1023u;
            unsigned int rk = pk[k] >> 10;
            binned[gb[b] + rk] = key[k];
        }
    }
}

// ---------------------------------------------------------------------------
// K4: per-bucket CSR finalize: rowptr, dinv, xs = x*dinv (fused), csr fill
// ---------------------------------------------------------------------------
__global__ __launch_bounds__(256) void k_csr(const unsigned int* __restrict__ binned,
                                             const int* __restrict__ bucketOff,
                                             const float* __restrict__ x,
                                             int* __restrict__ rowptr,
                                             float* __restrict__ dinv,
                                             float* __restrict__ xs,
                                             int* __restrict__ csr) {
    __shared__ int lcnt[256];
    __shared__ int lpre[256];
    __shared__ int sc[256];
    int b = blockIdx.x, t = threadIdx.x;
    int e0 = bucketOff[b], e1 = bucketOff[b + 1];
    lcnt[t] = 0;
    __syncthreads();
    for (int e = e0 + t; e < e1; e += 256)
        atomicAdd(&lcnt[binned[e] >> 18], 1);
    __syncthreads();
    int v = lcnt[t];
    sc[t] = v;
    __syncthreads();
    for (int o = 1; o < 256; o <<= 1) {
        int x2 = (t >= o) ? sc[t - o] : 0;
        __syncthreads();
        sc[t] += x2;
        __syncthreads();
    }
    int excl = sc[t] - v;
    lpre[t] = excl;
    int gnode = b * BS + t;
    if (gnode < N_NODES) {
        rowptr[gnode] = e0 + excl;
        float dv = rsqrtf((float)v + 1.0f);
        dinv[gnode] = dv;
        xs[gnode * 3 + 0] = x[gnode * 3 + 0] * dv;
        xs[gnode * 3 + 1] = x[gnode * 3 + 1] * dv;
        xs[gnode * 3 + 2] = x[gnode * 3 + 2] * dv;
    }
    lcnt[t] = 0;
    __syncthreads();
    for (int e = e0 + t; e < e1; e += 256) {
        unsigned int key = binned[e];
        int ld = key >> 18;
        int pos = atomicAdd(&lcnt[ld], 1);
        csr[e0 + lpre[ld] + pos] = (int)(key & 0x3FFFFu);
    }
}

// ---------------------------------------------------------------------------
// K5: layer-1 z-gather (1 thread/node): z = dd*(sum_src xs + xs[n]) (3-wide),
// write zs; accumulate per-graph S=sum z (3) and M=sum z z^T (6 unique) via
// LDS slot atomics (few per node; far below R8's contention scale), then
// flush ~72 global atomics per block into gstats[g*9].
// ---------------------------------------------------------------------------
__global__ __launch_bounds__(256) void k_gz(
        const float* __restrict__ xs, const int* __restrict__ csr,
        const int* __restrict__ rowptr, const float* __restrict__ dinv,
        const int* __restrict__ batch,
        float* __restrict__ zs, float* __restrict__ gstats) {
    __shared__ float st[8 * 12];
    __shared__ int gbase_s;
    int t = threadIdx.x;
    for (int i = t; i < 8 * 12; i += 256) st[i] = 0.f;
    if (t == 0) gbase_s = batch[blockIdx.x * 256];
    __syncthreads();

    int n = blockIdx.x * 256 + t;
    if (n < N_NODES) {
        float z0 = xs[n * 3 + 0], z1 = xs[n * 3 + 1], z2 = xs[n * 3 + 2];
        int e0 = rowptr[n], e1 = rowptr[n + 1];
        for (int e = e0; e < e1; ++e) {
            int s = csr[e];
            z0 += xs[s * 3 + 0];
            z1 += xs[s * 3 + 1];
            z2 += xs[s * 3 + 2];
        }
        float dd = dinv[n];
        z0 *= dd; z1 *= dd; z2 *= dd;
        zs[n * 3 + 0] = z0; zs[n * 3 + 1] = z1; zs[n * 3 + 2] = z2;
        int g = batch[n];
        int lg = g - gbase_s;
        if (lg < 8) {
            float* sp = &st[lg * 12];
            atomicAdd(&sp[0], z0);      atomicAdd(&sp[1], z1);
            atomicAdd(&sp[2], z2);      atomicAdd(&sp[3], z0 * z0);
            atomicAdd(&sp[4], z0 * z1); atomicAdd(&sp[5], z0 * z2);
            atomicAdd(&sp[6], z1 * z1); atomicAdd(&sp[7], z1 * z2);
            atomicAdd(&sp[8], z2 * z2);
        } else {
            float* gp = &gstats[g * 9];
            atomicAdd(&gp[0], z0);      atomicAdd(&gp[1], z1);
            atomicAdd(&gp[2], z2);      atomicAdd(&gp[3], z0 * z0);
            atomicAdd(&gp[4], z0 * z1); atomicAdd(&gp[5], z0 * z2);
            atomicAdd(&gp[6], z1 * z1); atomicAdd(&gp[7], z1 * z2);
            atomicAdd(&gp[8], z2 * z2);
        }
    }
    __syncthreads();
    if (t < 72) {
        int slot = t / 9, k = t % 9;
        int g = gbase_s + slot;
        float v = st[slot * 12 + k];
        if (g < N_GRAPHS && v != 0.f) atomicAdd(&gstats[g * 9 + k], v);
    }
}

// ---------------------------------------------------------------------------
// K6: per-(graph,feature) analytic GN1 stats: y = w_f.z + b_f =>
// mean = w.S/n + b ; E[y^2] = w^T M w /n + 2 b w.S/n + b^2 ;
// mv = ms*mean ; var = E[y^2] - 2 mv*mean + mv^2 ; sc = gw*rsqrt(var+eps)
// ---------------------------------------------------------------------------
__global__ __launch_bounds__(256) void k_prep(
        const float* __restrict__ gstats, const int* __restrict__ off,
        const float* __restrict__ W, const float* __restrict__ bias,
        const float* __restrict__ gw, const float* __restrict__ gb_unused,
        const float* __restrict__ gms,
        float* __restrict__ mvA, float* __restrict__ scA) {
    int gid = blockIdx.x * 256 + threadIdx.x;
    if (gid >= N_GRAPHS * F) return;
    int g = gid >> 5, f = gid & 31;
    float rc = 1.0f / (float)(off[g + 1] - off[g]);
    const float* sp = &gstats[g * 9];
    float S0 = sp[0], S1 = sp[1], S2 = sp[2];
    float m00 = sp[3], m01 = sp[4], m02 = sp[5], m11 = sp[6], m12 = sp[7], m22 = sp[8];
    float w0 = W[0 * F + f], w1 = W[1 * F + f], w2 = W[2 * F + f];
    float b = bias[f];
    float sy = w0 * S0 + w1 * S1 + w2 * S2;
    float m = sy * rc + b;
    float q = w0 * w0 * m00 + w1 * w1 * m11 + w2 * w2 * m22
            + 2.f * (w0 * w1 * m01 + w0 * w2 * m02 + w1 * w2 * m12);
    float Ey2 = q * rc + 2.f * b * (sy * rc) + b * b;
    float mv = gms[f] * m;
    float var = Ey2 - 2.f * mv * m + mv * mv;
    mvA[gid] = mv;
    scA[gid] = gw[f] * rsqrtf(var + EPSV);
}

// ---------------------------------------------------------------------------
// K7: layer-1 elementwise: y = z@W1 + b1 -> GN1 normalize -> ReLU ->
// write x1 (fp32) + xh (bf16, dinv-pre-scaled). 8 threads/node (4 feats each).
// ---------------------------------------------------------------------------
__global__ __launch_bounds__(256) void k_n1(
        const float* __restrict__ zs, const int* __restrict__ batch,
        const float* __restrict__ dinv,
        const float* __restrict__ W, const float* __restrict__ bias,
        const float* __restrict__ gb,
        const float* __restrict__ mvA, const float* __restrict__ scA,
        unsigned short* __restrict__ xh, float* __restrict__ outp) {
    int gid = blockIdx.x * 256 + threadIdx.x;
    int n = gid >> 3, c = gid & 7;
    if (n >= N_NODES) return;
    float z0 = zs[n * 3 + 0], z1 = zs[n * 3 + 1], z2 = zs[n * 3 + 2];
    int g = batch[n];
    float dd = dinv[n];
    float4 w0 = ((const float4*)(W + 0 * F))[c];
    float4 w1 = ((const float4*)(W + 1 * F))[c];
    float4 w2 = ((const float4*)(W + 2 * F))[c];
    float4 y  = ((const float4*)bias)[c];
    y.x += z0 * w0.x + z1 * w1.x + z2 * w2.x;
    y.y += z0 * w0.y + z1 * w1.y + z2 * w2.y;
    y.z += z0 * w0.z + z1 * w1.z + z2 * w2.z;
    y.w += z0 * w0.w + z1 * w1.w + z2 * w2.w;
    float4 mv = ((const float4*)mvA)[g * 8 + c];
    float4 sc = ((const float4*)scA)[g * 8 + c];
    float4 bb = ((const float4*)gb)[c];
    float4 o;
    o.x = fmaxf((y.x - mv.x) * sc.x + bb.x, 0.f);
    o.y = fmaxf((y.y - mv.y) * sc.y + bb.y, 0.f);
    o.z = fmaxf((y.z - mv.z) * sc.z + bb.z, 0.f);
    o.w = fmaxf((y.w - mv.w) * sc.w + bb.w, 0.f);
    ((float4*)outp)[n * 8 + c] = o;
    uint2 hp;
    hp.x = f2bf(o.x * dd) | (f2bf(o.y * dd) << 16);
    hp.y = f2bf(o.z * dd) | (f2bf(o.w * dd) << 16);
    ((uint2*)xh)[n * 8 + c] = hp;
}

// ---------------------------------------------------------------------------
// K8: aggregate(32-wide bf16 rows, self from xh) + transform(32->32) + bias.
// 4 threads/node, 16B loads, 4x-unrolled edge loop.
// ---------------------------------------------------------------------------
__global__ __launch_bounds__(256) void k_gat32(
        const unsigned short* __restrict__ xh, const int* __restrict__ csr,
        const int* __restrict__ rowptr, const float* __restrict__ dinv,
        const float* __restrict__ W, const float* __restrict__ bias,
        float* __restrict__ y) {
    __shared__ float Ws[F * F];     // 4 KB
    __shared__ float bs[F];
    __shared__ float Zs[64 * 36];   // 9 KB
    int t = threadIdx.x;
    ((float4*)Ws)[t] = ((const float4*)W)[t];
    if (t < F) bs[t] = bias[t];
    __syncthreads();

    int gid = blockIdx.x * 256 + t;
    int n = gid >> 2, c = gid & 3, ln = t >> 2;
    bool act = (n < N_NODES);
    float acc[8];
    if (act) {
        const uint4* xr = (const uint4*)xh;  // row = 4 x 16B
        uint4 us = xr[n * 4 + c];            // self: dd^2*x = dd*xh
        acc[0] = bflo(us.x); acc[1] = bfhi(us.x);
        acc[2] = bflo(us.y); acc[3] = bfhi(us.y);
        acc[4] = bflo(us.z); acc[5] = bfhi(us.z);
        acc[6] = bflo(us.w); acc[7] = bfhi(us.w);
        int e0 = rowptr[n], e1 = rowptr[n + 1];
        int e = e0;
        for (; e + 3 < e1; e += 4) {
            int s0 = csr[e], s1 = csr[e + 1], s2 = csr[e + 2], s3 = csr[e + 3];
            uint4 u0 = xr[s0 * 4 + c];
            uint4 u1 = xr[s1 * 4 + c];
            uint4 u2 = xr[s2 * 4 + c];
            uint4 u3 = xr[s3 * 4 + c];
            acc[0] += bflo(u0.x); acc[1] += bfhi(u0.x);
            acc[2] += bflo(u0.y); acc[3] += bfhi(u0.y);
            acc[4] += bflo(u0.z); acc[5] += bfhi(u0.z);
            acc[6] += bflo(u0.w); acc[7] += bfhi(u0.w);
            acc[0] += bflo(u1.x); acc[1] += bfhi(u1.x);
            acc[2] += bflo(u1.y); acc[3] += bfhi(u1.y);
            acc[4] += bflo(u1.z); acc[5] += bfhi(u1.z);
            acc[6] += bflo(u1.w); acc[7] += bfhi(u1.w);
            acc[0] += bflo(u2.x); acc[1] += bfhi(u2.x);
            acc[2] += bflo(u2.y); acc[3] += bfhi(u2.y);
            acc[4] += bflo(u2.z); acc[5] += bfhi(u2.z);
            acc[6] += bflo(u2.w); acc[7] += bfhi(u2.w);
            acc[0] += bflo(u3.x); acc[1] += bfhi(u3.x);
            acc[2] += bflo(u3.y); acc[3] += bfhi(u3.y);
            acc[4] += bflo(u3.z); acc[5] += bfhi(u3.z);
            acc[6] += bflo(u3.w); acc[7] += bfhi(u3.w);
        }
        for (; e < e1; ++e) {
            int s0 = csr[e];
            uint4 u0 = xr[s0 * 4 + c];
            acc[0] += bflo(u0.x); acc[1] += bfhi(u0.x);
            acc[2] += bflo(u0.y); acc[3] += bfhi(u0.y);
            acc[4] += bflo(u0.z); acc[5] += bfhi(u0.z);
            acc[6] += bflo(u0.w); acc[7] += bfhi(u0.w);
        }
        float dd = dinv[n];
#pragma unroll
        for (int j = 0; j < 8; ++j) acc[j] *= dd;
    } else {
#pragma unroll
        for (int j = 0; j < 8; ++j) acc[j] = 0.f;
    }
    *(float4*)&Zs[ln * 36 + c * 8]     = *(float4*)&acc[0];
    *(float4*)&Zs[ln * 36 + c * 8 + 4] = *(float4*)&acc[4];
    __syncthreads();

    if (act) {
        const float* zrow = &Zs[ln * 36];
        float4 o0 = ((const float4*)bs)[c * 2];
        float4 o1 = ((const float4*)bs)[c * 2 + 1];
#pragma unroll
        for (int k = 0; k < F; ++k) {
            float zk = zrow[k];
            float4 w0 = ((const float4*)&Ws[k * F])[c * 2];
            float4 w1 = ((const float4*)&Ws[k * F])[c * 2 + 1];
            o0.x += zk * w0.x; o0.y += zk * w0.y; o0.z += zk * w0.z; o0.w += zk * w0.w;
            o1.x += zk * w1.x; o1.y += zk * w1.y; o1.z += zk * w1.z; o1.w += zk * w1.w;
        }
        ((float4*)y)[n * 8 + c * 2]     = o0;
        ((float4*)y)[n * 8 + c * 2 + 1] = o1;
    }
}

// ---------------------------------------------------------------------------
// K9: GraphNorm, block per graph; single-pass stats, normalize pass L2-hot.
// In-place capable. Emits fp32 out + (WXH) bf16 dinv-pre-scaled xh.
// ---------------------------------------------------------------------------
template <bool RES, bool WXH>
__global__ __launch_bounds__(256) void k_gn2(
        const float* agg, const float* res, const int* __restrict__ off,
        const float* __restrict__ gw, const float* __restrict__ gb,
        const float* __restrict__ gms, const float* __restrict__ dinv,
        unsigned short* __restrict__ xh, float* outp) {
    __shared__ float red1[256], red2[256];
    __shared__ float mv_s[F], sc_s[F];
    int g = blockIdx.x;
    int i0 = off[g], i1 = off[g + 1];
    float rc = 1.0f / (float)(i1 - i0);
    int t = threadIdx.x;
    int f = t & 31, r0 = t >> 5;

    float s = 0.f, q = 0.f;
    for (int n = i0 + r0; n < i1; n += 8) {
        float v = agg[n * F + f];
        s += v; q += v * v;
    }
    red1[t] = s; red2[t] = q; __syncthreads();
    if (t < 128) { red1[t] += red1[t + 128]; red2[t] += red2[t + 128]; } __syncthreads();
    if (t < 64)  { red1[t] += red1[t + 64];  red2[t] += red2[t + 64];  } __syncthreads();
    if (t < 32) {
        float sm = (red1[t] + red1[t + 32]) * rc;
        float sq = (red2[t] + red2[t + 32]) * rc;
        float mv = gms[t] * sm;
        float var = sq - mv * (2.f * sm - mv);
        mv_s[t] = mv;
        sc_s[t] = gw[t] * rsqrtf(var + EPSV);
    }
    __syncthreads();

    float w = sc_s[f], mv = mv_s[f], bb = gb[f];
    for (int n = i0 + r0; n < i1; n += 8) {
        float y = (agg[n * F + f] - mv) * w + bb;
        if (RES) y += res[n * F + f];
        y = fmaxf(y, 0.f);
        outp[n * F + f] = y;
        if (WXH) xh[n * F + f] = (unsigned short)f2bf(y * dinv[n]);
    }
}

// ---------------------------------------------------------------------------
// K10: final GraphNorm + residual + ReLU + mean-pool + 32x3 linear
// ---------------------------------------------------------------------------
__global__ __launch_bounds__(256) void k_gnfin(
        const float* __restrict__ agg, const float* __restrict__ res,
        const int* __restrict__ off,
        const float* __restrict__ gw, const float* __restrict__ gb,
        const float* __restrict__ gms,
        const float* __restrict__ lin_w, const float* __restrict__ lin_b,
        float* __restrict__ outp) {
    __shared__ float red1[256], red2[256];
    __shared__ float mv_s[F], sc_s[F], pooled_s[F];
    int g = blockIdx.x;
    int i0 = off[g], i1 = off[g + 1];
    float cnt = (float)(i1 - i0);
    float rc = 1.0f / cnt;
    int t = threadIdx.x;
    int f = t & 31, r0 = t >> 5;

    float s = 0.f, q = 0.f;
    for (int n = i0 + r0; n < i1; n += 8) {
        float v = agg[n * F + f];
        s += v; q += v * v;
    }
    red1[t] = s; red2[t] = q; __syncthreads();
    if (t < 128) { red1[t] += red1[t + 128]; red2[t] += red2[t + 128]; } __syncthreads();
    if (t < 64)  { red1[t] += red1[t + 64];  red2[t] += red2[t + 64];  } __syncthreads();
    if (t < 32) {
        float sm = (red1[t] + red1[t + 32]) * rc;
        float sq = (red2[t] + red2[t + 32]) * rc;
        float mv = gms[t] * sm;
        float var = sq - mv * (2.f * sm - mv);
        mv_s[t] = mv;
        sc_s[t] = gw[t] * rsqrtf(var + EPSV);
    }
    __syncthreads();

    float w = sc_s[f], mv = mv_s[f], bb = gb[f];
    float ps = 0.f;
    for (int n = i0 + r0; n < i1; n += 8) {
        float yv = (agg[n * F + f] - mv) * w + bb + res[n * F + f];
        ps += fmaxf(yv, 0.f);
    }
    __syncthreads();
    red1[t] = ps; __syncthreads();
    if (t < 128) red1[t] += red1[t + 128]; __syncthreads();
    if (t < 64)  red1[t] += red1[t + 64];  __syncthreads();
    if (t < 32) { red1[t] += red1[t + 32]; pooled_s[t] = red1[t] * rc; }
    __syncthreads();
    if (t < 3) {
        float o = lin_b[t];
#pragma unroll
        for (int f2 = 0; f2 < F; ++f2) o += pooled_s[f2] * lin_w[f2 * 3 + t];
        outp[g * 3 + t] = o;
    }
}

// ---------------------------------------------------------------------------
extern "C" void kernel_launch(void* const* d_in, const int* in_sizes, int n_in,
                              void* d_out, int out_size, void* d_ws, size_t ws_size,
                              hipStream_t stream) {
    const float* x      = (const float*)d_in[0];
    const int*   ei     = (const int*)d_in[1];
    const int*   batch  = (const int*)d_in[2];
    const float* W1     = (const float*)d_in[3];
    const float* b1     = (const float*)d_in[4];
    const float* gn1w   = (const float*)d_in[5];
    const float* gn1b   = (const float*)d_in[6];
    const float* gn1ms  = (const float*)d_in[7];
    const float* W2     = (const float*)d_in[8];
    const float* b2     = (const float*)d_in[9];
    const float* gn2w   = (const float*)d_in[10];
    const float* gn2b   = (const float*)d_in[11];
    const float* gn2ms  = (const float*)d_in[12];
    const float* W3     = (const float*)d_in[13];
    const float* b3     = (const float*)d_in[14];
    const float* gn3w   = (const float*)d_in[15];
    const float* gn3b   = (const float*)d_in[16];
    const float* gn3ms  = (const float*)d_in[17];
    const float* lin_w  = (const float*)d_in[18];
    const float* lin_b  = (const float*)d_in[19];
    float* out = (float*)d_out;

    const int* srcp = ei;
    const int* dstp = ei + N_EDGES;

    char* ws = (char*)d_ws;
    size_t p = 0;
    auto alloc = [&](size_t bytes) {
        size_t r = p; p += (bytes + 511) & ~(size_t)511; return r;
    };
    int*   off       = (int*)  (ws + alloc(sizeof(int) * (N_GRAPHS + 1)));
    int*   bucketCnt = (int*)  (ws + alloc(sizeof(int) * NB));
    int*   bucketOff = (int*)  (ws + alloc(sizeof(int) * (NB + 1)));
    int*   bucketCur = (int*)  (ws + alloc(sizeof(int) * NB));
    int*   rowptr    = (int*)  (ws + alloc(sizeof(int) * (N_NODES + 1)));
    float* dinv      = (float*)(ws + alloc(sizeof(float) * N_NODES));
    float* xs        = (float*)(ws + alloc(sizeof(float) * N_NODES * 3));
    float* zs        = (float*)(ws + alloc(sizeof(float) * N_NODES * 3));
    float* gstats    = (float*)(ws + alloc(sizeof(float) * N_GRAPHS * 9));
    float* mvA       = (float*)(ws + alloc(sizeof(float) * N_GRAPHS * F));
    float* scA       = (float*)(ws + alloc(sizeof(float) * N_GRAPHS * F));
    unsigned int* binned = (unsigned int*)(ws + alloc(sizeof(unsigned int) * N_EDGES));
    int*   csr       = (int*)  (ws + alloc(sizeof(int) * N_EDGES));
    float* A         = (float*)(ws + alloc(sizeof(float) * N_NODES * F));
    float* B         = (float*)(ws + alloc(sizeof(float) * N_NODES * F));
    // xh aliases binned (dead after k_csr); both exactly 9.6 MB.
    unsigned short* xh = (unsigned short*)binned;
    (void)ws_size; (void)n_in; (void)in_sizes; (void)out_size;

    const int TB = 256;
    dim3 blk(TB);
    int ngrid  = (N_NODES + TB - 1) / TB;
    int ggrid8 = (N_NODES * 8 + TB - 1) / TB;
    int ggrid4 = (N_NODES * 4 + TB - 1) / TB;

    hipMemsetAsync(gstats, 0, sizeof(float) * N_GRAPHS * 9, stream);

    // CSR build via bucketed counting sort (+ dinv, xs fused into k_csr)
    k_init <<<ngrid, blk, 0, stream>>>(batch, bucketCnt, off, rowptr);
    k_bhist<<<NEB, blk, 0, stream>>>(dstp, bucketCnt);
    k_bscan<<<1, blk, 0, stream>>>(bucketCnt, bucketOff, bucketCur);
    k_bin  <<<NEB, blk, 0, stream>>>(srcp, dstp, bucketCur, binned);
    k_csr  <<<NB, blk, 0, stream>>>(binned, bucketOff, x, rowptr, dinv, xs, csr);

    // layer 1 (analytic GN stats from 3-dim z moments)
    k_gz  <<<ngrid, blk, 0, stream>>>(xs, csr, rowptr, dinv, batch, zs, gstats);
    k_prep<<<(N_GRAPHS * F + TB - 1) / TB, blk, 0, stream>>>(
        gstats, off, W1, b1, gn1w, gn1b, gn1ms, mvA, scA);
    k_n1  <<<ggrid8, blk, 0, stream>>>(zs, batch, dinv, W1, b1, gn1b, mvA, scA, xh, A);

    // layer 2: gather(xh)+transform -> B ; GN + res(A) in-place -> x2=B (+ xh)
    k_gat32<<<ggrid4, blk, 0, stream>>>(xh, csr, rowptr, dinv, W2, b2, B);
    k_gn2<true, true><<<N_GRAPHS, blk, 0, stream>>>(
        B, A, off, gn2w, gn2b, gn2ms, dinv, xh, B);

    // layer 3: gather(xh)+transform -> A ; GN + res(B) + pool + linear -> out
    k_gat32<<<ggrid4, blk, 0, stream>>>(xh, csr, rowptr, dinv, W3, b3, A);
    k_gnfin<<<N_GRAPHS, blk, 0, stream>>>(A, B, off, gn3w, gn3b, gn3ms,
                                          lin_w, lin_b, out);
}

// Round 12
// 316.008 us; speedup vs baseline: 3.5704x; 1.0530x over previous
//
#include <hip/hip_runtime.h>

#define N_NODES 150000
#define N_EDGES 2400000
#define N_GRAPHS 1024
#define F 32
#define EPSV 1e-5f

#define BS 256                                   // nodes per dst-bucket
#define NB ((N_NODES + BS - 1) / BS)             // 586 buckets
#define CAP 5120                                 // fixed bucket capacity (E[c]=4096, +16 sigma)
#define EB 8192                                  // edges per binning block
#define NEB ((N_EDGES + EB - 1) / EB)            // 293 blocks
#define EPT (EB / 256)                           // 32 edges per thread

// bf16 helpers (RTN-even encode; decode via shift/mask)
__device__ __forceinline__ float bflo(unsigned int u) {
    union { unsigned int i; float f; } v; v.i = u << 16; return v.f;
}
__device__ __forceinline__ float bfhi(unsigned int u) {
    union { unsigned int i; float f; } v; v.i = u & 0xffff0000u; return v.f;
}
__device__ __forceinline__ unsigned int f2bf(float f) {
    union { float f; unsigned int i; } v; v.f = f;
    unsigned int r = v.i + 0x7fff + ((v.i >> 16) & 1);
    return r >> 16;
}

// ---------------------------------------------------------------------------
// K0: graph offsets from sorted batch; seed bucket cursors to b*CAP; zero gstats
// ---------------------------------------------------------------------------
__global__ void k_init(const int* __restrict__ batch, int* __restrict__ bucketCur,
                       int* __restrict__ off, float* __restrict__ gstats) {
    int i = blockIdx.x * blockDim.x + threadIdx.x;
    if (i >= N_NODES) return;
    if (i < NB) bucketCur[i] = i * CAP;
    if (i < N_GRAPHS * 9) gstats[i] = 0.f;
    int b = batch[i];
    if (i == 0) {
        for (int g = 0; g <= b; ++g) off[g] = 0;
    } else {
        int pb = batch[i - 1];
        for (int g = pb + 1; g <= b; ++g) off[g] = i;
    }
    if (i == N_NODES - 1) {
        for (int g = b + 1; g <= N_GRAPHS; ++g) off[g] = N_NODES;
    }
}

// ---------------------------------------------------------------------------
// K1: bin edges into fixed-capacity buckets. key = (localdst << 18) | src.
// ---------------------------------------------------------------------------
__global__ __launch_bounds__(256) void k_bin(const int* __restrict__ src,
                                             const int* __restrict__ dst,
                                             int* __restrict__ bucketCur,
                                             unsigned int* __restrict__ binned) {
    __shared__ int h[NB];
    __shared__ int gb[NB];
    int t = threadIdx.x;
    for (int b = t; b < NB; b += 256) h[b] = 0;
    __syncthreads();
    int base = blockIdx.x * EB + t;
    unsigned int key[EPT];
    unsigned int pk[EPT];               // (rank<<10) | bucket ; 0xFFFFFFFF = inactive
#pragma unroll
    for (int k = 0; k < EPT; ++k) {
        int e = base + k * 256;
        if (e < N_EDGES) {
            int d = dst[e];
            int b = d >> 8;
            key[k] = ((unsigned int)(d & 255) << 18) | (unsigned int)src[e];
            unsigned int rk = (unsigned int)atomicAdd(&h[b], 1);
            pk[k] = (rk << 10) | (unsigned int)b;
        } else {
            pk[k] = 0xFFFFFFFFu;
        }
    }
    __syncthreads();
    for (int b = t; b < NB; b += 256) {
        int c = h[b];
        gb[b] = c ? atomicAdd(&bucketCur[b], c) : 0;
    }
    __syncthreads();
#pragma unroll
    for (int k = 0; k < EPT; ++k) {
        if (pk[k] != 0xFFFFFFFFu) {
            unsigned int b = pk[k] & 1023u;
            unsigned int rk = pk[k] >> 10;
            binned[gb[b] + rk] = key[k];
        }
    }
}

// ---------------------------------------------------------------------------
// K2: per-bucket CSR finalize: packed rowptr=(start<<8)|deg, dinv, xs=x*dinv,
// csr fill (bucket-local region b*CAP..).
// ---------------------------------------------------------------------------
__global__ __launch_bounds__(256) void k_csr(const unsigned int* __restrict__ binned,
                                             const int* __restrict__ bucketCur,
                                             const float* __restrict__ x,
                                             unsigned int* __restrict__ rowptr,
                                             float* __restrict__ dinv,
                                             float* __restrict__ xs,
                                             int* __restrict__ csr) {
    __shared__ int lcnt[256];
    __shared__ int lpre[256];
    __shared__ int sc[256];
    int b = blockIdx.x, t = threadIdx.x;
    int e0 = b * CAP;
    int e1 = bucketCur[b];              // final cursor = b*CAP + count
    lcnt[t] = 0;
    __syncthreads();
    for (int e = e0 + t; e < e1; e += 256)
        atomicAdd(&lcnt[binned[e] >> 18], 1);
    __syncthreads();
    int v = lcnt[t];
    sc[t] = v;
    __syncthreads();
    for (int o = 1; o < 256; o <<= 1) {
        int x2 = (t >= o) ? sc[t - o] : 0;
        __syncthreads();
        sc[t] += x2;
        __syncthreads();
    }
    int excl = sc[t] - v;
    lpre[t] = excl;
    int gnode = b * BS + t;
    if (gnode < N_NODES) {
        rowptr[gnode] = ((unsigned int)(e0 + excl) << 8) | (unsigned int)min(v, 255);
        float dv = rsqrtf((float)v + 1.0f);
        dinv[gnode] = dv;
        xs[gnode * 3 + 0] = x[gnode * 3 + 0] * dv;
        xs[gnode * 3 + 1] = x[gnode * 3 + 1] * dv;
        xs[gnode * 3 + 2] = x[gnode * 3 + 2] * dv;
    }
    lcnt[t] = 0;
    __syncthreads();
    for (int e = e0 + t; e < e1; e += 256) {
        unsigned int key = binned[e];
        int ld = key >> 18;
        int pos = atomicAdd(&lcnt[ld], 1);
        csr[e0 + lpre[ld] + pos] = (int)(key & 0x3FFFFu);
    }
}

// ---------------------------------------------------------------------------
// K3: layer-1 z-gather (1 thread/node) + per-graph moment stats (S, M).
// int4 csr loads (4-aligned peel). LDS slot atomics + ~72 global atomics/blk.
// ---------------------------------------------------------------------------
__global__ __launch_bounds__(256) void k_gz(
        const float* __restrict__ xs, const int* __restrict__ csr,
        const unsigned int* __restrict__ rowptr, const float* __restrict__ dinv,
        const int* __restrict__ batch,
        float* __restrict__ zs, float* __restrict__ gstats) {
    __shared__ float st[8 * 12];
    __shared__ int gbase_s;
    int t = threadIdx.x;
    for (int i = t; i < 8 * 12; i += 256) st[i] = 0.f;
    if (t == 0) gbase_s = batch[blockIdx.x * 256];
    __syncthreads();

    int n = blockIdx.x * 256 + t;
    if (n < N_NODES) {
        float z0 = xs[n * 3 + 0], z1 = xs[n * 3 + 1], z2 = xs[n * 3 + 2];
        unsigned int rp = rowptr[n];
        int e = (int)(rp >> 8);
        int e1 = e + (int)(rp & 255u);
        for (; e < e1 && (e & 3); ++e) {
            int s = csr[e];
            z0 += xs[s * 3 + 0]; z1 += xs[s * 3 + 1]; z2 += xs[s * 3 + 2];
        }
        for (; e + 3 < e1; e += 4) {
            int4 ss = *(const int4*)(csr + e);
            z0 += xs[ss.x * 3 + 0]; z1 += xs[ss.x * 3 + 1]; z2 += xs[ss.x * 3 + 2];
            z0 += xs[ss.y * 3 + 0]; z1 += xs[ss.y * 3 + 1]; z2 += xs[ss.y * 3 + 2];
            z0 += xs[ss.z * 3 + 0]; z1 += xs[ss.z * 3 + 1]; z2 += xs[ss.z * 3 + 2];
            z0 += xs[ss.w * 3 + 0]; z1 += xs[ss.w * 3 + 1]; z2 += xs[ss.w * 3 + 2];
        }
        for (; e < e1; ++e) {
            int s = csr[e];
            z0 += xs[s * 3 + 0]; z1 += xs[s * 3 + 1]; z2 += xs[s * 3 + 2];
        }
        float dd = dinv[n];
        z0 *= dd; z1 *= dd; z2 *= dd;
        zs[n * 3 + 0] = z0; zs[n * 3 + 1] = z1; zs[n * 3 + 2] = z2;
        int g = batch[n];
        int lg = g - gbase_s;
        if (lg < 8) {
            float* sp = &st[lg * 12];
            atomicAdd(&sp[0], z0);      atomicAdd(&sp[1], z1);
            atomicAdd(&sp[2], z2);      atomicAdd(&sp[3], z0 * z0);
            atomicAdd(&sp[4], z0 * z1); atomicAdd(&sp[5], z0 * z2);
            atomicAdd(&sp[6], z1 * z1); atomicAdd(&sp[7], z1 * z2);
            atomicAdd(&sp[8], z2 * z2);
        } else {
            float* gp = &gstats[g * 9];
            atomicAdd(&gp[0], z0);      atomicAdd(&gp[1], z1);
            atomicAdd(&gp[2], z2);      atomicAdd(&gp[3], z0 * z0);
            atomicAdd(&gp[4], z0 * z1); atomicAdd(&gp[5], z0 * z2);
            atomicAdd(&gp[6], z1 * z1); atomicAdd(&gp[7], z1 * z2);
            atomicAdd(&gp[8], z2 * z2);
        }
    }
    __syncthreads();
    if (t < 72) {
        int slot = t / 9, k = t % 9;
        int g = gbase_s + slot;
        float v = st[slot * 12 + k];
        if (g < N_GRAPHS && v != 0.f) atomicAdd(&gstats[g * 9 + k], v);
    }
}

// ---------------------------------------------------------------------------
// K4: analytic GN1 per-(graph,feature) stats from z moments.
// ---------------------------------------------------------------------------
__global__ __launch_bounds__(256) void k_prep(
        const float* __restrict__ gstats, const int* __restrict__ off,
        const float* __restrict__ W, const float* __restrict__ bias,
        const float* __restrict__ gw, const float* __restrict__ gms,
        float* __restrict__ mvA, float* __restrict__ scA) {
    int gid = blockIdx.x * 256 + threadIdx.x;
    if (gid >= N_GRAPHS * F) return;
    int g = gid >> 5, f = gid & 31;
    float rc = 1.0f / (float)(off[g + 1] - off[g]);
    const float* sp = &gstats[g * 9];
    float S0 = sp[0], S1 = sp[1], S2 = sp[2];
    float m00 = sp[3], m01 = sp[4], m02 = sp[5], m11 = sp[6], m12 = sp[7], m22 = sp[8];
    float w0 = W[0 * F + f], w1 = W[1 * F + f], w2 = W[2 * F + f];
    float b = bias[f];
    float sy = w0 * S0 + w1 * S1 + w2 * S2;
    float m = sy * rc + b;
    float q = w0 * w0 * m00 + w1 * w1 * m11 + w2 * w2 * m22
            + 2.f * (w0 * w1 * m01 + w0 * w2 * m02 + w1 * w2 * m12);
    float Ey2 = q * rc + 2.f * b * (sy * rc) + b * b;
    float mv = gms[f] * m;
    float var = Ey2 - 2.f * mv * m + mv * mv;
    mvA[gid] = mv;
    scA[gid] = gw[f] * rsqrtf(var + EPSV);
}

// ---------------------------------------------------------------------------
// K5: layer-1 elementwise: y=z@W1+b1 -> normalize -> ReLU -> x1 + bf16 xh.
// ---------------------------------------------------------------------------
__global__ __launch_bounds__(256) void k_n1(
        const float* __restrict__ zs, const int* __restrict__ batch,
        const float* __restrict__ dinv,
        const float* __restrict__ W, const float* __restrict__ bias,
        const float* __restrict__ gb,
        const float* __restrict__ mvA, const float* __restrict__ scA,
        unsigned short* __restrict__ xh, float* __restrict__ outp) {
    int gid = blockIdx.x * 256 + threadIdx.x;
    int n = gid >> 3, c = gid & 7;
    if (n >= N_NODES) return;
    float z0 = zs[n * 3 + 0], z1 = zs[n * 3 + 1], z2 = zs[n * 3 + 2];
    int g = batch[n];
    float dd = dinv[n];
    float4 w0 = ((const float4*)(W + 0 * F))[c];
    float4 w1 = ((const float4*)(W + 1 * F))[c];
    float4 w2 = ((const float4*)(W + 2 * F))[c];
    float4 y  = ((const float4*)bias)[c];
    y.x += z0 * w0.x + z1 * w1.x + z2 * w2.x;
    y.y += z0 * w0.y + z1 * w1.y + z2 * w2.y;
    y.z += z0 * w0.z + z1 * w1.z + z2 * w2.z;
    y.w += z0 * w0.w + z1 * w1.w + z2 * w2.w;
    float4 mv = ((const float4*)mvA)[g * 8 + c];
    float4 sc = ((const float4*)scA)[g * 8 + c];
    float4 bb = ((const float4*)gb)[c];
    float4 o;
    o.x = fmaxf((y.x - mv.x) * sc.x + bb.x, 0.f);
    o.y = fmaxf((y.y - mv.y) * sc.y + bb.y, 0.f);
    o.z = fmaxf((y.z - mv.z) * sc.z + bb.z, 0.f);
    o.w = fmaxf((y.w - mv.w) * sc.w + bb.w, 0.f);
    ((float4*)outp)[n * 8 + c] = o;
    uint2 hp;
    hp.x = f2bf(o.x * dd) | (f2bf(o.y * dd) << 16);
    hp.y = f2bf(o.z * dd) | (f2bf(o.w * dd) << 16);
    ((uint2*)xh)[n * 8 + c] = hp;
}

// ---------------------------------------------------------------------------
// K6: aggregate(32-wide bf16 rows, self from xh) + transform(32->32) + bias.
// 4 threads/node; int4 csr loads (uniform across the 4 lanes -> broadcast).
// ---------------------------------------------------------------------------
__global__ __launch_bounds__(256) void k_gat32(
        const unsigned short* __restrict__ xh, const int* __restrict__ csr,
        const unsigned int* __restrict__ rowptr, const float* __restrict__ dinv,
        const float* __restrict__ W, const float* __restrict__ bias,
        float* __restrict__ y) {
    __shared__ float Ws[F * F];     // 4 KB
    __shared__ float bs[F];
    __shared__ float Zs[64 * 36];   // 9 KB
    int t = threadIdx.x;
    ((float4*)Ws)[t] = ((const float4*)W)[t];
    if (t < F) bs[t] = bias[t];
    __syncthreads();

    int gid = blockIdx.x * 256 + t;
    int n = gid >> 2, c = gid & 3, ln = t >> 2;
    bool act = (n < N_NODES);
    float acc[8];
    if (act) {
        const uint4* xr = (const uint4*)xh;  // row = 4 x 16B
        uint4 us = xr[n * 4 + c];            // self: dd^2*x = dd*xh
        acc[0] = bflo(us.x); acc[1] = bfhi(us.x);
        acc[2] = bflo(us.y); acc[3] = bfhi(us.y);
        acc[4] = bflo(us.z); acc[5] = bfhi(us.z);
        acc[6] = bflo(us.w); acc[7] = bfhi(us.w);
        unsigned int rp = rowptr[n];
        int e = (int)(rp >> 8);
        int e1 = e + (int)(rp & 255u);
        for (; e < e1 && (e & 3); ++e) {
            int s0 = csr[e];
            uint4 u0 = xr[s0 * 4 + c];
            acc[0] += bflo(u0.x); acc[1] += bfhi(u0.x);
            acc[2] += bflo(u0.y); acc[3] += bfhi(u0.y);
            acc[4] += bflo(u0.z); acc[5] += bfhi(u0.z);
            acc[6] += bflo(u0.w); acc[7] += bfhi(u0.w);
        }
        for (; e + 3 < e1; e += 4) {
            int4 ss = *(const int4*)(csr + e);
            uint4 u0 = xr[ss.x * 4 + c];
            uint4 u1 = xr[ss.y * 4 + c];
            uint4 u2 = xr[ss.z * 4 + c];
            uint4 u3 = xr[ss.w * 4 + c];
            acc[0] += bflo(u0.x); acc[1] += bfhi(u0.x);
            acc[2] += bflo(u0.y); acc[3] += bfhi(u0.y);
            acc[4] += bflo(u0.z); acc[5] += bfhi(u0.z);
            acc[6] += bflo(u0.w); acc[7] += bfhi(u0.w);
            acc[0] += bflo(u1.x); acc[1] += bfhi(u1.x);
            acc[2] += bflo(u1.y); acc[3] += bfhi(u1.y);
            acc[4] += bflo(u1.z); acc[5] += bfhi(u1.z);
            acc[6] += bflo(u1.w); acc[7] += bfhi(u1.w);
            acc[0] += bflo(u2.x); acc[1] += bfhi(u2.x);
            acc[2] += bflo(u2.y); acc[3] += bfhi(u2.y);
            acc[4] += bflo(u2.z); acc[5] += bfhi(u2.z);
            acc[6] += bflo(u2.w); acc[7] += bfhi(u2.w);
            acc[0] += bflo(u3.x); acc[1] += bfhi(u3.x);
            acc[2] += bflo(u3.y); acc[3] += bfhi(u3.y);
            acc[4] += bflo(u3.z); acc[5] += bfhi(u3.z);
            acc[6] += bflo(u3.w); acc[7] += bfhi(u3.w);
        }
        for (; e < e1; ++e) {
            int s0 = csr[e];
            uint4 u0 = xr[s0 * 4 + c];
            acc[0] += bflo(u0.x); acc[1] += bfhi(u0.x);
            acc[2] += bflo(u0.y); acc[3] += bfhi(u0.y);
            acc[4] += bflo(u0.z); acc[5] += bfhi(u0.z);
            acc[6] += bflo(u0.w); acc[7] += bfhi(u0.w);
        }
        float dd = dinv[n];
#pragma unroll
        for (int j = 0; j < 8; ++j) acc[j] *= dd;
    } else {
#pragma unroll
        for (int j = 0; j < 8; ++j) acc[j] = 0.f;
    }
    *(float4*)&Zs[ln * 36 + c * 8]     = *(float4*)&acc[0];
    *(float4*)&Zs[ln * 36 + c * 8 + 4] = *(float4*)&acc[4];
    __syncthreads();

    if (act) {
        const float* zrow = &Zs[ln * 36];
        float4 o0 = ((const float4*)bs)[c * 2];
        float4 o1 = ((const float4*)bs)[c * 2 + 1];
#pragma unroll
        for (int k = 0; k < F; ++k) {
            float zk = zrow[k];
            float4 w0 = ((const float4*)&Ws[k * F])[c * 2];
            float4 w1 = ((const float4*)&Ws[k * F])[c * 2 + 1];
            o0.x += zk * w0.x; o0.y += zk * w0.y; o0.z += zk * w0.z; o0.w += zk * w0.w;
            o1.x += zk * w1.x; o1.y += zk * w1.y; o1.z += zk * w1.z; o1.w += zk * w1.w;
        }
        ((float4*)y)[n * 8 + c * 2]     = o0;
        ((float4*)y)[n * 8 + c * 2 + 1] = o1;
    }
}

// ---------------------------------------------------------------------------
// K7: GraphNorm, block per graph; single-pass stats, normalize pass L2-hot.
// In-place capable. Emits fp32 out + (WXH) bf16 dinv-pre-scaled xh.
// ---------------------------------------------------------------------------
template <bool RES, bool WXH>
__global__ __launch_bounds__(256) void k_gn2(
        const float* agg, const float* res, const int* __restrict__ off,
        const float* __restrict__ gw, const float* __restrict__ gb,
        const float* __restrict__ gms, const float* __restrict__ dinv,
        unsigned short* __restrict__ xh, float* outp) {
    __shared__ float red1[256], red2[256];
    __shared__ float mv_s[F], sc_s[F];
    int g = blockIdx.x;
    int i0 = off[g], i1 = off[g + 1];
    float rc = 1.0f / (float)(i1 - i0);
    int t = threadIdx.x;
    int f = t & 31, r0 = t >> 5;

    float s = 0.f, q = 0.f;
    for (int n = i0 + r0; n < i1; n += 8) {
        float v = agg[n * F + f];
        s += v; q += v * v;
    }
    red1[t] = s; red2[t] = q; __syncthreads();
    if (t < 128) { red1[t] += red1[t + 128]; red2[t] += red2[t + 128]; } __syncthreads();
    if (t < 64)  { red1[t] += red1[t + 64];  red2[t] += red2[t + 64];  } __syncthreads();
    if (t < 32) {
        float sm = (red1[t] + red1[t + 32]) * rc;
        float sq = (red2[t] + red2[t + 32]) * rc;
        float mv = gms[t] * sm;
        float var = sq - mv * (2.f * sm - mv);
        mv_s[t] = mv;
        sc_s[t] = gw[t] * rsqrtf(var + EPSV);
    }
    __syncthreads();

    float w = sc_s[f], mv = mv_s[f], bb = gb[f];
    for (int n = i0 + r0; n < i1; n += 8) {
        float y = (agg[n * F + f] - mv) * w + bb;
        if (RES) y += res[n * F + f];
        y = fmaxf(y, 0.f);
        outp[n * F + f] = y;
        if (WXH) xh[n * F + f] = (unsigned short)f2bf(y * dinv[n]);
    }
}

// ---------------------------------------------------------------------------
// K8: final GraphNorm + residual + ReLU + mean-pool + 32x3 linear
// ---------------------------------------------------------------------------
__global__ __launch_bounds__(256) void k_gnfin(
        const float* __restrict__ agg, const float* __restrict__ res,
        const int* __restrict__ off,
        const float* __restrict__ gw, const float* __restrict__ gb,
        const float* __restrict__ gms,
        const float* __restrict__ lin_w, const float* __restrict__ lin_b,
        float* __restrict__ outp) {
    __shared__ float red1[256], red2[256];
    __shared__ float mv_s[F], sc_s[F], pooled_s[F];
    int g = blockIdx.x;
    int i0 = off[g], i1 = off[g + 1];
    float cnt = (float)(i1 - i0);
    float rc = 1.0f / cnt;
    int t = threadIdx.x;
    int f = t & 31, r0 = t >> 5;

    float s = 0.f, q = 0.f;
    for (int n = i0 + r0; n < i1; n += 8) {
        float v = agg[n * F + f];
        s += v; q += v * v;
    }
    red1[t] = s; red2[t] = q; __syncthreads();
    if (t < 128) { red1[t] += red1[t + 128]; red2[t] += red2[t + 128]; } __syncthreads();
    if (t < 64)  { red1[t] += red1[t + 64];  red2[t] += red2[t + 64];  } __syncthreads();
    if (t < 32) {
        float sm = (red1[t] + red1[t + 32]) * rc;
        float sq = (red2[t] + red2[t + 32]) * rc;
        float mv = gms[t] * sm;
        float var = sq - mv * (2.f * sm - mv);
        mv_s[t] = mv;
        sc_s[t] = gw[t] * rsqrtf(var + EPSV);
    }
    __syncthreads();

    float w = sc_s[f], mv = mv_s[f], bb = gb[f];
    float ps = 0.f;
    for (int n = i0 + r0; n < i1; n += 8) {
        float yv = (agg[n * F + f] - mv) * w + bb + res[n * F + f];
        ps += fmaxf(yv, 0.f);
    }
    __syncthreads();
    red1[t] = ps; __syncthreads();
    if (t < 128) red1[t] += red1[t + 128]; __syncthreads();
    if (t < 64)  red1[t] += red1[t + 64];  __syncthreads();
    if (t < 32) { red1[t] += red1[t + 32]; pooled_s[t] = red1[t] * rc; }
    __syncthreads();
    if (t < 3) {
        float o = lin_b[t];
#pragma unroll
        for (int f2 = 0; f2 < F; ++f2) o += pooled_s[f2] * lin_w[f2 * 3 + t];
        outp[g * 3 + t] = o;
    }
}

// ---------------------------------------------------------------------------
extern "C" void kernel_launch(void* const* d_in, const int* in_sizes, int n_in,
                              void* d_out, int out_size, void* d_ws, size_t ws_size,
                              hipStream_t stream) {
    const float* x      = (const float*)d_in[0];
    const int*   ei     = (const int*)d_in[1];
    const int*   batch  = (const int*)d_in[2];
    const float* W1     = (const float*)d_in[3];
    const float* b1     = (const float*)d_in[4];
    const float* gn1w   = (const float*)d_in[5];
    const float* gn1b   = (const float*)d_in[6];
    const float* gn1ms  = (const float*)d_in[7];
    const float* W2     = (const float*)d_in[8];
    const float* b2     = (const float*)d_in[9];
    const float* gn2w   = (const float*)d_in[10];
    const float* gn2b   = (const float*)d_in[11];
    const float* gn2ms  = (const float*)d_in[12];
    const float* W3     = (const float*)d_in[13];
    const float* b3     = (const float*)d_in[14];
    const float* gn3w   = (const float*)d_in[15];
    const float* gn3b   = (const float*)d_in[16];
    const float* gn3ms  = (const float*)d_in[17];
    const float* lin_w  = (const float*)d_in[18];
    const float* lin_b  = (const float*)d_in[19];
    float* out = (float*)d_out;

    const int* srcp = ei;
    const int* dstp = ei + N_EDGES;

    char* ws = (char*)d_ws;
    size_t p = 0;
    auto alloc = [&](size_t bytes) {
        size_t r = p; p += (bytes + 511) & ~(size_t)511; return r;
    };
    int*   off       = (int*)  (ws + alloc(sizeof(int) * (N_GRAPHS + 1)));
    int*   bucketCur = (int*)  (ws + alloc(sizeof(int) * NB));
    unsigned int* rowptr = (unsigned int*)(ws + alloc(sizeof(unsigned int) * N_NODES));
    float* dinv      = (float*)(ws + alloc(sizeof(float) * N_NODES));
    float* xs        = (float*)(ws + alloc(sizeof(float) * N_NODES * 3));
    float* zs        = (float*)(ws + alloc(sizeof(float) * N_NODES * 3));
    float* gstats    = (float*)(ws + alloc(sizeof(float) * N_GRAPHS * 9));
    float* mvA       = (float*)(ws + alloc(sizeof(float) * N_GRAPHS * F));
    float* scA       = (float*)(ws + alloc(sizeof(float) * N_GRAPHS * F));
    unsigned int* binned = (unsigned int*)(ws + alloc(sizeof(unsigned int) * NB * CAP));
    int*   csr       = (int*)  (ws + alloc(sizeof(int) * NB * CAP));
    float* A         = (float*)(ws + alloc(sizeof(float) * N_NODES * F));
    float* B         = (float*)(ws + alloc(sizeof(float) * N_NODES * F));
    // xh aliases binned (dead after k_csr); xh 9.6 MB <= binned 12 MB.
    unsigned short* xh = (unsigned short*)binned;
    (void)ws_size; (void)n_in; (void)in_sizes; (void)out_size;

    const int TB = 256;
    dim3 blk(TB);
    int ngrid  = (N_NODES + TB - 1) / TB;
    int ggrid8 = (N_NODES * 8 + TB - 1) / TB;
    int ggrid4 = (N_NODES * 4 + TB - 1) / TB;

    // build: init (off, cursors, gstats) -> bin (fixed-cap buckets) -> csr
    k_init<<<ngrid, blk, 0, stream>>>(batch, bucketCur, off, gstats);
    k_bin <<<NEB, blk, 0, stream>>>(srcp, dstp, bucketCur, binned);
    k_csr <<<NB, blk, 0, stream>>>(binned, bucketCur, x, rowptr, dinv, xs, csr);

    // layer 1 (analytic GN stats from 3-dim z moments)
    k_gz  <<<ngrid, blk, 0, stream>>>(xs, csr, rowptr, dinv, batch, zs, gstats);
    k_prep<<<(N_GRAPHS * F + TB - 1) / TB, blk, 0, stream>>>(
        gstats, off, W1, b1, gn1w, gn1ms, mvA, scA);
    k_n1  <<<ggrid8, blk, 0, stream>>>(zs, batch, dinv, W1, b1, gn1b, mvA, scA, xh, A);

    // layer 2: gather(xh)+transform -> B ; GN + res(A) in-place -> x2=B (+ xh)
    k_gat32<<<ggrid4, blk, 0, stream>>>(xh, csr, rowptr, dinv, W2, b2, B);
    k_gn2<true, true><<<N_GRAPHS, blk, 0, stream>>>(
        B, A, off, gn2w, gn2b, gn2ms, dinv, xh, B);

    // layer 3: gather(xh)+transform -> A ; GN + res(B) + pool + linear -> out
    k_gat32<<<ggrid4, blk, 0, stream>>>(xh, csr, rowptr, dinv, W3, b3, A);
    k_gnfin<<<N_GRAPHS, blk, 0, stream>>>(A, B, off, gn3w, gn3b, gn3ms,
                                          lin_w, lin_b, out);
}

// Round 13
// 311.269 us; speedup vs baseline: 3.6247x; 1.0152x over previous
//
#include <hip/hip_runtime.h>

#define N_NODES 150000
#define N_EDGES 2400000
#define N_GRAPHS 1024
#define F 32
#define EPSV 1e-5f

#define BS 256                                   // nodes per dst-bucket
#define NB ((N_NODES + BS - 1) / BS)             // 586 buckets
#define CAP 5120                                 // fixed bucket capacity (+16 sigma)
#define EB 8192                                  // edges per binning block
#define NEB ((N_EDGES + EB - 1) / EB)            // 293 blocks
#define EPT (EB / 256)                           // 32 edges per thread
#define KPT (CAP / 256)                          // 20 cached keys per thread in k_csr

// bf16 helpers (RTN-even encode; decode via shift/mask)
__device__ __forceinline__ float bflo(unsigned int u) {
    union { unsigned int i; float f; } v; v.i = u << 16; return v.f;
}
__device__ __forceinline__ float bfhi(unsigned int u) {
    union { unsigned int i; float f; } v; v.i = u & 0xffff0000u; return v.f;
}
__device__ __forceinline__ unsigned int f2bf(float f) {
    union { float f; unsigned int i; } v; v.f = f;
    unsigned int r = v.i + 0x7fff + ((v.i >> 16) & 1);
    return r >> 16;
}

// ---------------------------------------------------------------------------
// K0: graph offsets from sorted batch; seed bucket cursors; zero gstats
// ---------------------------------------------------------------------------
__global__ void k_init(const int* __restrict__ batch, int* __restrict__ bucketCur,
                       int* __restrict__ off, float* __restrict__ gstats) {
    int i = blockIdx.x * blockDim.x + threadIdx.x;
    if (i >= N_NODES) return;
    if (i < NB) bucketCur[i] = i * CAP;
    if (i < N_GRAPHS * 9) gstats[i] = 0.f;
    int b = batch[i];
    if (i == 0) {
        for (int g = 0; g <= b; ++g) off[g] = 0;
    } else {
        int pb = batch[i - 1];
        for (int g = pb + 1; g <= b; ++g) off[g] = i;
    }
    if (i == N_NODES - 1) {
        for (int g = b + 1; g <= N_GRAPHS; ++g) off[g] = N_NODES;
    }
}

// ---------------------------------------------------------------------------
// K1: bin edges into fixed-capacity buckets. key = (localdst << 18) | src.
// ---------------------------------------------------------------------------
__global__ __launch_bounds__(256) void k_bin(const int* __restrict__ src,
                                             const int* __restrict__ dst,
                                             int* __restrict__ bucketCur,
                                             unsigned int* __restrict__ binned) {
    __shared__ int h[NB];
    __shared__ int gb[NB];
    int t = threadIdx.x;
    for (int b = t; b < NB; b += 256) h[b] = 0;
    __syncthreads();
    int base = blockIdx.x * EB + t;
    unsigned int key[EPT];
    unsigned int pk[EPT];               // (rank<<10) | bucket ; 0xFFFFFFFF = inactive
#pragma unroll
    for (int k = 0; k < EPT; ++k) {
        int e = base + k * 256;
        if (e < N_EDGES) {
            int d = dst[e];
            int b = d >> 8;
            key[k] = ((unsigned int)(d & 255) << 18) | (unsigned int)src[e];
            unsigned int rk = (unsigned int)atomicAdd(&h[b], 1);
            pk[k] = (rk << 10) | (unsigned int)b;
        } else {
            pk[k] = 0xFFFFFFFFu;
        }
    }
    __syncthreads();
    for (int b = t; b < NB; b += 256) {
        int c = h[b];
        gb[b] = c ? atomicAdd(&bucketCur[b], c) : 0;
    }
    __syncthreads();
#pragma unroll
    for (int k = 0; k < EPT; ++k) {
        if (pk[k] != 0xFFFFFFFFu) {
            unsigned int b = pk[k] & 1023u;
            unsigned int rk = pk[k] >> 10;
            binned[gb[b] + rk] = key[k];
        }
    }
}

// ---------------------------------------------------------------------------
// K2: per-bucket CSR finalize with register-cached keys (single binned read):
// packed rowptr=(start<<8)|deg, dinv, xs4=x*dinv (stride 4), csr fill.
// ---------------------------------------------------------------------------
__global__ __launch_bounds__(256) void k_csr(const unsigned int* __restrict__ binned,
                                             const int* __restrict__ bucketCur,
                                             const float* __restrict__ x,
                                             unsigned int* __restrict__ rowptr,
                                             float* __restrict__ dinv,
                                             float* __restrict__ xs4,
                                             int* __restrict__ csr) {
    __shared__ int lcnt[256];
    __shared__ int lpre[256];
    __shared__ int sc[256];
    int b = blockIdx.x, t = threadIdx.x;
    int e0 = b * CAP;
    int e1 = bucketCur[b];              // final cursor = b*CAP + count
    lcnt[t] = 0;
    __syncthreads();
    unsigned int kc[KPT];
#pragma unroll
    for (int k = 0; k < KPT; ++k) {
        int e = e0 + t + k * 256;
        if (e < e1) {
            kc[k] = binned[e];
            atomicAdd(&lcnt[kc[k] >> 18], 1);
        }
    }
    __syncthreads();
    int v = lcnt[t];
    sc[t] = v;
    __syncthreads();
    for (int o = 1; o < 256; o <<= 1) {
        int x2 = (t >= o) ? sc[t - o] : 0;
        __syncthreads();
        sc[t] += x2;
        __syncthreads();
    }
    int excl = sc[t] - v;
    lpre[t] = excl;
    int gnode = b * BS + t;
    if (gnode < N_NODES) {
        rowptr[gnode] = ((unsigned int)(e0 + excl) << 8) | (unsigned int)min(v, 255);
        float dv = rsqrtf((float)v + 1.0f);
        dinv[gnode] = dv;
        float4 xv;
        xv.x = x[gnode * 3 + 0] * dv;
        xv.y = x[gnode * 3 + 1] * dv;
        xv.z = x[gnode * 3 + 2] * dv;
        xv.w = 0.f;
        ((float4*)xs4)[gnode] = xv;
    }
    lcnt[t] = 0;
    __syncthreads();
#pragma unroll
    for (int k = 0; k < KPT; ++k) {
        int e = e0 + t + k * 256;
        if (e < e1) {
            unsigned int key = kc[k];
            int ld = key >> 18;
            int pos = atomicAdd(&lcnt[ld], 1);
            csr[e0 + lpre[ld] + pos] = (int)(key & 0x3FFFFu);
        }
    }
}

// ---------------------------------------------------------------------------
// K3: layer-1 z-gather (1 thread/node) + per-graph moment stats (S, M).
// float4 xs loads; int4 csr loads (per-thread independent streams).
// ---------------------------------------------------------------------------
__global__ __launch_bounds__(256) void k_gz(
        const float* __restrict__ xs4, const int* __restrict__ csr,
        const unsigned int* __restrict__ rowptr, const float* __restrict__ dinv,
        const int* __restrict__ batch,
        float* __restrict__ zs4, float* __restrict__ gstats) {
    __shared__ float st[8 * 12];
    __shared__ int gbase_s;
    int t = threadIdx.x;
    for (int i = t; i < 8 * 12; i += 256) st[i] = 0.f;
    if (t == 0) gbase_s = batch[blockIdx.x * 256];
    __syncthreads();

    int n = blockIdx.x * 256 + t;
    if (n < N_NODES) {
        const float4* xv = (const float4*)xs4;
        float4 sv = xv[n];
        float z0 = sv.x, z1 = sv.y, z2 = sv.z;
        unsigned int rp = rowptr[n];
        int e = (int)(rp >> 8);
        int e1 = e + (int)(rp & 255u);
        for (; e < e1 && (e & 3); ++e) {
            float4 u = xv[csr[e]];
            z0 += u.x; z1 += u.y; z2 += u.z;
        }
        for (; e + 3 < e1; e += 4) {
            int4 ss = *(const int4*)(csr + e);
            float4 u0 = xv[ss.x], u1 = xv[ss.y], u2 = xv[ss.z], u3 = xv[ss.w];
            z0 += u0.x + u1.x + u2.x + u3.x;
            z1 += u0.y + u1.y + u2.y + u3.y;
            z2 += u0.z + u1.z + u2.z + u3.z;
        }
        for (; e < e1; ++e) {
            float4 u = xv[csr[e]];
            z0 += u.x; z1 += u.y; z2 += u.z;
        }
        float dd = dinv[n];
        z0 *= dd; z1 *= dd; z2 *= dd;
        float4 zv; zv.x = z0; zv.y = z1; zv.z = z2; zv.w = 0.f;
        ((float4*)zs4)[n] = zv;
        int g = batch[n];
        int lg = g - gbase_s;
        if (lg < 8) {
            float* sp = &st[lg * 12];
            atomicAdd(&sp[0], z0);      atomicAdd(&sp[1], z1);
            atomicAdd(&sp[2], z2);      atomicAdd(&sp[3], z0 * z0);
            atomicAdd(&sp[4], z0 * z1); atomicAdd(&sp[5], z0 * z2);
            atomicAdd(&sp[6], z1 * z1); atomicAdd(&sp[7], z1 * z2);
            atomicAdd(&sp[8], z2 * z2);
        } else {
            float* gp = &gstats[g * 9];
            atomicAdd(&gp[0], z0);      atomicAdd(&gp[1], z1);
            atomicAdd(&gp[2], z2);      atomicAdd(&gp[3], z0 * z0);
            atomicAdd(&gp[4], z0 * z1); atomicAdd(&gp[5], z0 * z2);
            atomicAdd(&gp[6], z1 * z1); atomicAdd(&gp[7], z1 * z2);
            atomicAdd(&gp[8], z2 * z2);
        }
    }
    __syncthreads();
    if (t < 72) {
        int slot = t / 9, k = t % 9;
        int g = gbase_s + slot;
        float v = st[slot * 12 + k];
        if (g < N_GRAPHS && v != 0.f) atomicAdd(&gstats[g * 9 + k], v);
    }
}

// ---------------------------------------------------------------------------
// K4: analytic GN1 per-(graph,feature) stats from z moments.
// ---------------------------------------------------------------------------
__global__ __launch_bounds__(256) void k_prep(
        const float* __restrict__ gstats, const int* __restrict__ off,
        const float* __restrict__ W, const float* __restrict__ bias,
        const float* __restrict__ gw, const float* __restrict__ gms,
        float* __restrict__ mvA, float* __restrict__ scA) {
    int gid = blockIdx.x * 256 + threadIdx.x;
    if (gid >= N_GRAPHS * F) return;
    int g = gid >> 5, f = gid & 31;
    float rc = 1.0f / (float)(off[g + 1] - off[g]);
    const float* sp = &gstats[g * 9];
    float S0 = sp[0], S1 = sp[1], S2 = sp[2];
    float m00 = sp[3], m01 = sp[4], m02 = sp[5], m11 = sp[6], m12 = sp[7], m22 = sp[8];
    float w0 = W[0 * F + f], w1 = W[1 * F + f], w2 = W[2 * F + f];
    float b = bias[f];
    float sy = w0 * S0 + w1 * S1 + w2 * S2;
    float m = sy * rc + b;
    float q = w0 * w0 * m00 + w1 * w1 * m11 + w2 * w2 * m22
            + 2.f * (w0 * w1 * m01 + w0 * w2 * m02 + w1 * w2 * m12);
    float Ey2 = q * rc + 2.f * b * (sy * rc) + b * b;
    float mv = gms[f] * m;
    float var = Ey2 - 2.f * mv * m + mv * mv;
    mvA[gid] = mv;
    scA[gid] = gw[f] * rsqrtf(var + EPSV);
}

// ---------------------------------------------------------------------------
// K5: layer-1 elementwise: y=z@W1+b1 -> normalize -> ReLU -> x1 + bf16 xh.
// ---------------------------------------------------------------------------
__global__ __launch_bounds__(256) void k_n1(
        const float* __restrict__ zs4, const int* __restrict__ batch,
        const float* __restrict__ dinv,
        const float* __restrict__ W, const float* __restrict__ bias,
        const float* __restrict__ gb,
        const float* __restrict__ mvA, const float* __restrict__ scA,
        unsigned short* __restrict__ xh, float* __restrict__ outp) {
    int gid = blockIdx.x * 256 + threadIdx.x;
    int n = gid >> 3, c = gid & 7;
    if (n >= N_NODES) return;
    float4 zv = ((const float4*)zs4)[n];
    float z0 = zv.x, z1 = zv.y, z2 = zv.z;
    int g = batch[n];
    float dd = dinv[n];
    float4 w0 = ((const float4*)(W + 0 * F))[c];
    float4 w1 = ((const float4*)(W + 1 * F))[c];
    float4 w2 = ((const float4*)(W + 2 * F))[c];
    float4 y  = ((const float4*)bias)[c];
    y.x += z0 * w0.x + z1 * w1.x + z2 * w2.x;
    y.y += z0 * w0.y + z1 * w1.y + z2 * w2.y;
    y.z += z0 * w0.z + z1 * w1.z + z2 * w2.z;
    y.w += z0 * w0.w + z1 * w1.w + z2 * w2.w;
    float4 mv = ((const float4*)mvA)[g * 8 + c];
    float4 sc = ((const float4*)scA)[g * 8 + c];
    float4 bb = ((const float4*)gb)[c];
    float4 o;
    o.x = fmaxf((y.x - mv.x) * sc.x + bb.x, 0.f);
    o.y = fmaxf((y.y - mv.y) * sc.y + bb.y, 0.f);
    o.z = fmaxf((y.z - mv.z) * sc.z + bb.z, 0.f);
    o.w = fmaxf((y.w - mv.w) * sc.w + bb.w, 0.f);
    ((float4*)outp)[n * 8 + c] = o;
    uint2 hp;
    hp.x = f2bf(o.x * dd) | (f2bf(o.y * dd) << 16);
    hp.y = f2bf(o.z * dd) | (f2bf(o.w * dd) << 16);
    ((uint2*)xh)[n * 8 + c] = hp;
}

// ---------------------------------------------------------------------------
// K6: aggregate(32-wide bf16 rows, self from xh) + transform(32->32) + bias.
// 4 threads/node, scalar csr loads (L1-broadcast), 4x-unrolled edge loop,
// packed rowptr single load. (R10 body + packed rowptr — measured-best combo.)
// ---------------------------------------------------------------------------
__global__ __launch_bounds__(256) void k_gat32(
        const unsigned short* __restrict__ xh, const int* __restrict__ csr,
        const unsigned int* __restrict__ rowptr, const float* __restrict__ dinv,
        const float* __restrict__ W, const float* __restrict__ bias,
        float* __restrict__ y) {
    __shared__ float Ws[F * F];     // 4 KB
    __shared__ float bs[F];
    __shared__ float Zs[64 * 36];   // 9 KB
    int t = threadIdx.x;
    ((float4*)Ws)[t] = ((const float4*)W)[t];
    if (t < F) bs[t] = bias[t];
    __syncthreads();

    int gid = blockIdx.x * 256 + t;
    int n = gid >> 2, c = gid & 3, ln = t >> 2;
    bool act = (n < N_NODES);
    float acc[8];
    if (act) {
        const uint4* xr = (const uint4*)xh;  // row = 4 x 16B
        uint4 us = xr[n * 4 + c];            // self: dd^2*x = dd*xh
        acc[0] = bflo(us.x); acc[1] = bfhi(us.x);
        acc[2] = bflo(us.y); acc[3] = bfhi(us.y);
        acc[4] = bflo(us.z); acc[5] = bfhi(us.z);
        acc[6] = bflo(us.w); acc[7] = bfhi(us.w);
        unsigned int rp = rowptr[n];
        int e = (int)(rp >> 8);
        int e1 = e + (int)(rp & 255u);
        for (; e + 3 < e1; e += 4) {
            int s0 = csr[e], s1 = csr[e + 1], s2 = csr[e + 2], s3 = csr[e + 3];
            uint4 u0 = xr[s0 * 4 + c];
            uint4 u1 = xr[s1 * 4 + c];
            uint4 u2 = xr[s2 * 4 + c];
            uint4 u3 = xr[s3 * 4 + c];
            acc[0] += bflo(u0.x); acc[1] += bfhi(u0.x);
            acc[2] += bflo(u0.y); acc[3] += bfhi(u0.y);
            acc[4] += bflo(u0.z); acc[5] += bfhi(u0.z);
            acc[6] += bflo(u0.w); acc[7] += bfhi(u0.w);
            acc[0] += bflo(u1.x); acc[1] += bfhi(u1.x);
            acc[2] += bflo(u1.y); acc[3] += bfhi(u1.y);
            acc[4] += bflo(u1.z); acc[5] += bfhi(u1.z);
            acc[6] += bflo(u1.w); acc[7] += bfhi(u1.w);
            acc[0] += bflo(u2.x); acc[1] += bfhi(u2.x);
            acc[2] += bflo(u2.y); acc[3] += bfhi(u2.y);
            acc[4] += bflo(u2.z); acc[5] += bfhi(u2.z);
            acc[6] += bflo(u2.w); acc[7] += bfhi(u2.w);
            acc[0] += bflo(u3.x); acc[1] += bfhi(u3.x);
            acc[2] += bflo(u3.y); acc[3] += bfhi(u3.y);
            acc[4] += bflo(u3.z); acc[5] += bfhi(u3.z);
            acc[6] += bflo(u3.w); acc[7] += bfhi(u3.w);
        }
        for (; e < e1; ++e) {
            int s0 = csr[e];
            uint4 u0 = xr[s0 * 4 + c];
            acc[0] += bflo(u0.x); acc[1] += bfhi(u0.x);
            acc[2] += bflo(u0.y); acc[3] += bfhi(u0.y);
            acc[4] += bflo(u0.z); acc[5] += bfhi(u0.z);
            acc[6] += bflo(u0.w); acc[7] += bfhi(u0.w);
        }
        float dd = dinv[n];
#pragma unroll
        for (int j = 0; j < 8; ++j) acc[j] *= dd;
    } else {
#pragma unroll
        for (int j = 0; j < 8; ++j) acc[j] = 0.f;
    }
    *(float4*)&Zs[ln * 36 + c * 8]     = *(float4*)&acc[0];
    *(float4*)&Zs[ln * 36 + c * 8 + 4] = *(float4*)&acc[4];
    __syncthreads();

    if (act) {
        const float* zrow = &Zs[ln * 36];
        float4 o0 = ((const float4*)bs)[c * 2];
        float4 o1 = ((const float4*)bs)[c * 2 + 1];
#pragma unroll
        for (int k = 0; k < F; ++k) {
            float zk = zrow[k];
            float4 w0 = ((const float4*)&Ws[k * F])[c * 2];
            float4 w1 = ((const float4*)&Ws[k * F])[c * 2 + 1];
            o0.x += zk * w0.x; o0.y += zk * w0.y; o0.z += zk * w0.z; o0.w += zk * w0.w;
            o1.x += zk * w1.x; o1.y += zk * w1.y; o1.z += zk * w1.z; o1.w += zk * w1.w;
        }
        ((float4*)y)[n * 8 + c * 2]     = o0;
        ((float4*)y)[n * 8 + c * 2 + 1] = o1;
    }
}

// ---------------------------------------------------------------------------
// K7: GraphNorm, block per graph; single-pass stats, normalize pass L2-hot.
// In-place capable. Emits fp32 out + (WXH) bf16 dinv-pre-scaled xh.
// ---------------------------------------------------------------------------
template <bool RES, bool WXH>
__global__ __launch_bounds__(256) void k_gn2(
        const float* agg, const float* res, const int* __restrict__ off,
        const float* __restrict__ gw, const float* __restrict__ gb,
        const float* __restrict__ gms, const float* __restrict__ dinv,
        unsigned short* __restrict__ xh, float* outp) {
    __shared__ float red1[256], red2[256];
    __shared__ float mv_s[F], sc_s[F];
    int g = blockIdx.x;
    int i0 = off[g], i1 = off[g + 1];
    float rc = 1.0f / (float)(i1 - i0);
    int t = threadIdx.x;
    int f = t & 31, r0 = t >> 5;

    float s = 0.f, q = 0.f;
    for (int n = i0 + r0; n < i1; n += 8) {
        float v = agg[n * F + f];
        s += v; q += v * v;
    }
    red1[t] = s; red2[t] = q; __syncthreads();
    if (t < 128) { red1[t] += red1[t + 128]; red2[t] += red2[t + 128]; } __syncthreads();
    if (t < 64)  { red1[t] += red1[t + 64];  red2[t] += red2[t + 64];  } __syncthreads();
    if (t < 32) {
        float sm = (red1[t] + red1[t + 32]) * rc;
        float sq = (red2[t] + red2[t + 32]) * rc;
        float mv = gms[t] * sm;
        float var = sq - mv * (2.f * sm - mv);
        mv_s[t] = mv;
        sc_s[t] = gw[t] * rsqrtf(var + EPSV);
    }
    __syncthreads();

    float w = sc_s[f], mv = mv_s[f], bb = gb[f];
    for (int n = i0 + r0; n < i1; n += 8) {
        float y = (agg[n * F + f] - mv) * w + bb;
        if (RES) y += res[n * F + f];
        y = fmaxf(y, 0.f);
        outp[n * F + f] = y;
        if (WXH) xh[n * F + f] = (unsigned short)f2bf(y * dinv[n]);
    }
}

// ---------------------------------------------------------------------------
// K8: final GraphNorm + residual + ReLU + mean-pool + 32x3 linear
// ---------------------------------------------------------------------------
__global__ __launch_bounds__(256) void k_gnfin(
        const float* __restrict__ agg, const float* __restrict__ res,
        const int* __restrict__ off,
        const float* __restrict__ gw, const float* __restrict__ gb,
        const float* __restrict__ gms,
        const float* __restrict__ lin_w, const float* __restrict__ lin_b,
        float* __restrict__ outp) {
    __shared__ float red1[256], red2[256];
    __shared__ float mv_s[F], sc_s[F], pooled_s[F];
    int g = blockIdx.x;
    int i0 = off[g], i1 = off[g + 1];
    float cnt = (float)(i1 - i0);
    float rc = 1.0f / cnt;
    int t = threadIdx.x;
    int f = t & 31, r0 = t >> 5;

    float s = 0.f, q = 0.f;
    for (int n = i0 + r0; n < i1; n += 8) {
        float v = agg[n * F + f];
        s += v; q += v * v;
    }
    red1[t] = s; red2[t] = q; __syncthreads();
    if (t < 128) { red1[t] += red1[t + 128]; red2[t] += red2[t + 128]; } __syncthreads();
    if (t < 64)  { red1[t] += red1[t + 64];  red2[t] += red2[t + 64];  } __syncthreads();
    if (t < 32) {
        float sm = (red1[t] + red1[t + 32]) * rc;
        float sq = (red2[t] + red2[t + 32]) * rc;
        float mv = gms[t] * sm;
        float var = sq - mv * (2.f * sm - mv);
        mv_s[t] = mv;
        sc_s[t] = gw[t] * rsqrtf(var + EPSV);
    }
    __syncthreads();

    float w = sc_s[f], mv = mv_s[f], bb = gb[f];
    float ps = 0.f;
    for (int n = i0 + r0; n < i1; n += 8) {
        float yv = (agg[n * F + f] - mv) * w + bb + res[n * F + f];
        ps += fmaxf(yv, 0.f);
    }
    __syncthreads();
    red1[t] = ps; __syncthreads();
    if (t < 128) red1[t] += red1[t + 128]; __syncthreads();
    if (t < 64)  red1[t] += red1[t + 64];  __syncthreads();
    if (t < 32) { red1[t] += red1[t + 32]; pooled_s[t] = red1[t] * rc; }
    __syncthreads();
    if (t < 3) {
        float o = lin_b[t];
#pragma unroll
        for (int f2 = 0; f2 < F; ++f2) o += pooled_s[f2] * lin_w[f2 * 3 + t];
        outp[g * 3 + t] = o;
    }
}

// ---------------------------------------------------------------------------
extern "C" void kernel_launch(void* const* d_in, const int* in_sizes, int n_in,
                              void* d_out, int out_size, void* d_ws, size_t ws_size,
                              hipStream_t stream) {
    const float* x      = (const float*)d_in[0];
    const int*   ei     = (const int*)d_in[1];
    const int*   batch  = (const int*)d_in[2];
    const float* W1     = (const float*)d_in[3];
    const float* b1     = (const float*)d_in[4];
    const float* gn1w   = (const float*)d_in[5];
    const float* gn1b   = (const float*)d_in[6];
    const float* gn1ms  = (const float*)d_in[7];
    const float* W2     = (const float*)d_in[8];
    const float* b2     = (const float*)d_in[9];
    const float* gn2w   = (const float*)d_in[10];
    const float* gn2b   = (const float*)d_in[11];
    const float* gn2ms  = (const float*)d_in[12];
    const float* W3     = (const float*)d_in[13];
    const float* b3     = (const float*)d_in[14];
    const float* gn3w   = (const float*)d_in[15];
    const float* gn3b   = (const float*)d_in[16];
    const float* gn3ms  = (const float*)d_in[17];
    const float* lin_w  = (const float*)d_in[18];
    const float* lin_b  = (const float*)d_in[19];
    float* out = (float*)d_out;

    const int* srcp = ei;
    const int* dstp = ei + N_EDGES;

    char* ws = (char*)d_ws;
    size_t p = 0;
    auto alloc = [&](size_t bytes) {
        size_t r = p; p += (bytes + 511) & ~(size_t)511; return r;
    };
    int*   off       = (int*)  (ws + alloc(sizeof(int) * (N_GRAPHS + 1)));
    int*   bucketCur = (int*)  (ws + alloc(sizeof(int) * NB));
    unsigned int* rowptr = (unsigned int*)(ws + alloc(sizeof(unsigned int) * N_NODES));
    float* dinv      = (float*)(ws + alloc(sizeof(float) * N_NODES));
    float* xs4       = (float*)(ws + alloc(sizeof(float) * N_NODES * 4));
    float* zs4       = (float*)(ws + alloc(sizeof(float) * N_NODES * 4));
    float* gstats    = (float*)(ws + alloc(sizeof(float) * N_GRAPHS * 9));
    float* mvA       = (float*)(ws + alloc(sizeof(float) * N_GRAPHS * F));
    float* scA       = (float*)(ws + alloc(sizeof(float) * N_GRAPHS * F));
    unsigned int* binned = (unsigned int*)(ws + alloc(sizeof(unsigned int) * NB * CAP));
    int*   csr       = (int*)  (ws + alloc(sizeof(int) * NB * CAP));
    float* A         = (float*)(ws + alloc(sizeof(float) * N_NODES * F));
    float* B         = (float*)(ws + alloc(sizeof(float) * N_NODES * F));
    // xh aliases binned (dead after k_csr); xh 9.6 MB <= binned 12 MB.
    unsigned short* xh = (unsigned short*)binned;
    (void)ws_size; (void)n_in; (void)in_sizes; (void)out_size;

    const int TB = 256;
    dim3 blk(TB);
    int ngrid  = (N_NODES + TB - 1) / TB;
    int ggrid8 = (N_NODES * 8 + TB - 1) / TB;
    int ggrid4 = (N_NODES * 4 + TB - 1) / TB;

    // build: init (off, cursors, gstats) -> bin (fixed-cap buckets) -> csr
    k_init<<<ngrid, blk, 0, stream>>>(batch, bucketCur, off, gstats);
    k_bin <<<NEB, blk, 0, stream>>>(srcp, dstp, bucketCur, binned);
    k_csr <<<NB, blk, 0, stream>>>(binned, bucketCur, x, rowptr, dinv, xs4, csr);

    // layer 1 (analytic GN stats from 3-dim z moments)
    k_gz  <<<ngrid, blk, 0, stream>>>(xs4, csr, rowptr, dinv, batch, zs4, gstats);
    k_prep<<<(N_GRAPHS * F + TB - 1) / TB, blk, 0, stream>>>(
        gstats, off, W1, b1, gn1w, gn1ms, mvA, scA);
    k_n1  <<<ggrid8, blk, 0, stream>>>(zs4, batch, dinv, W1, b1, gn1b, mvA, scA, xh, A);

    // layer 2: gather(xh)+transform -> B ; GN + res(A) in-place -> x2=B (+ xh)
    k_gat32<<<ggrid4, blk, 0, stream>>>(xh, csr, rowptr, dinv, W2, b2, B);
    k_gn2<true, true><<<N_GRAPHS, blk, 0, stream>>>(
        B, A, off, gn2w, gn2b, gn2ms, dinv, xh, B);

    // layer 3: gather(xh)+transform -> A ; GN + res(B) + pool + linear -> out
    k_gat32<<<ggrid4, blk, 0, stream>>>(xh, csr, rowptr, dinv, W3, b3, A);
    k_gnfin<<<N_GRAPHS, blk, 0, stream>>>(A, B, off, gn3w, gn3b, gn3ms,
                                          lin_w, lin_b, out);
}

// Round 14
// 305.366 us; speedup vs baseline: 3.6948x; 1.0193x over previous
//
#include <hip/hip_runtime.h>

#define N_NODES 150000
#define N_EDGES 2400000
#define N_GRAPHS 1024
#define F 32
#define EPSV 1e-5f

#define BS 256                                   // nodes per dst-bucket
#define NB ((N_NODES + BS - 1) / BS)             // 586 buckets
#define CAP 5120                                 // fixed bucket capacity (+16 sigma)
#define EB 8192                                  // edges per binning block
#define NEB ((N_EDGES + EB - 1) / EB)            // 293 blocks
#define EPT (EB / 256)                           // 32 edges per thread
#define KPT (CAP / 256)                          // 20 cached keys per thread in k_csr

// bf16 helpers (RTN-even encode; decode via shift/mask)
__device__ __forceinline__ float bflo(unsigned int u) {
    union { unsigned int i; float f; } v; v.i = u << 16; return v.f;
}
__device__ __forceinline__ float bfhi(unsigned int u) {
    union { unsigned int i; float f; } v; v.i = u & 0xffff0000u; return v.f;
}
__device__ __forceinline__ unsigned int f2bf(float f) {
    union { float f; unsigned int i; } v; v.f = f;
    unsigned int r = v.i + 0x7fff + ((v.i >> 16) & 1);
    return r >> 16;
}

// ---------------------------------------------------------------------------
// K0: graph offsets from sorted batch; seed bucket cursors; zero gstats
// ---------------------------------------------------------------------------
__global__ void k_init(const int* __restrict__ batch, int* __restrict__ bucketCur,
                       int* __restrict__ off, float* __restrict__ gstats) {
    int i = blockIdx.x * blockDim.x + threadIdx.x;
    if (i >= N_NODES) return;
    if (i < NB) bucketCur[i] = i * CAP;
    if (i < N_GRAPHS * 9) gstats[i] = 0.f;
    int b = batch[i];
    if (i == 0) {
        for (int g = 0; g <= b; ++g) off[g] = 0;
    } else {
        int pb = batch[i - 1];
        for (int g = pb + 1; g <= b; ++g) off[g] = i;
    }
    if (i == N_NODES - 1) {
        for (int g = b + 1; g <= N_GRAPHS; ++g) off[g] = N_NODES;
    }
}

// ---------------------------------------------------------------------------
// K1: bin edges into fixed-capacity buckets. key = (localdst << 18) | src.
// ---------------------------------------------------------------------------
__global__ __launch_bounds__(256) void k_bin(const int* __restrict__ src,
                                             const int* __restrict__ dst,
                                             int* __restrict__ bucketCur,
                                             unsigned int* __restrict__ binned) {
    __shared__ int h[NB];
    __shared__ int gb[NB];
    int t = threadIdx.x;
    for (int b = t; b < NB; b += 256) h[b] = 0;
    __syncthreads();
    int base = blockIdx.x * EB + t;
    unsigned int key[EPT];
    unsigned int pk[EPT];               // (rank<<10) | bucket ; 0xFFFFFFFF = inactive
#pragma unroll
    for (int k = 0; k < EPT; ++k) {
        int e = base + k * 256;
        if (e < N_EDGES) {
            int d = dst[e];
            int b = d >> 8;
            key[k] = ((unsigned int)(d & 255) << 18) | (unsigned int)src[e];
            unsigned int rk = (unsigned int)atomicAdd(&h[b], 1);
            pk[k] = (rk << 10) | (unsigned int)b;
        } else {
            pk[k] = 0xFFFFFFFFu;
        }
    }
    __syncthreads();
    for (int b = t; b < NB; b += 256) {
        int c = h[b];
        gb[b] = c ? atomicAdd(&bucketCur[b], c) : 0;
    }
    __syncthreads();
#pragma unroll
    for (int k = 0; k < EPT; ++k) {
        if (pk[k] != 0xFFFFFFFFu) {
            unsigned int b = pk[k] & 1023u;
            unsigned int rk = pk[k] >> 10;
            binned[gb[b] + rk] = key[k];
        }
    }
}

// ---------------------------------------------------------------------------
// K2: per-bucket CSR finalize with register-cached keys (single binned read):
// packed rowptr=(start<<8)|deg, dinv, xs4=x*dinv (stride 4), csr fill.
// ---------------------------------------------------------------------------
__global__ __launch_bounds__(256) void k_csr(const unsigned int* __restrict__ binned,
                                             const int* __restrict__ bucketCur,
                                             const float* __restrict__ x,
                                             unsigned int* __restrict__ rowptr,
                                             float* __restrict__ dinv,
                                             float* __restrict__ xs4,
                                             int* __restrict__ csr) {
    __shared__ int lcnt[256];
    __shared__ int lpre[256];
    __shared__ int sc[256];
    int b = blockIdx.x, t = threadIdx.x;
    int e0 = b * CAP;
    int e1 = bucketCur[b];              // final cursor = b*CAP + count
    lcnt[t] = 0;
    __syncthreads();
    unsigned int kc[KPT];
#pragma unroll
    for (int k = 0; k < KPT; ++k) {
        int e = e0 + t + k * 256;
        if (e < e1) {
            kc[k] = binned[e];
            atomicAdd(&lcnt[kc[k] >> 18], 1);
        }
    }
    __syncthreads();
    int v = lcnt[t];
    sc[t] = v;
    __syncthreads();
    for (int o = 1; o < 256; o <<= 1) {
        int x2 = (t >= o) ? sc[t - o] : 0;
        __syncthreads();
        sc[t] += x2;
        __syncthreads();
    }
    int excl = sc[t] - v;
    lpre[t] = excl;
    int gnode = b * BS + t;
    if (gnode < N_NODES) {
        rowptr[gnode] = ((unsigned int)(e0 + excl) << 8) | (unsigned int)min(v, 255);
        float dv = rsqrtf((float)v + 1.0f);
        dinv[gnode] = dv;
        float4 xv;
        xv.x = x[gnode * 3 + 0] * dv;
        xv.y = x[gnode * 3 + 1] * dv;
        xv.z = x[gnode * 3 + 2] * dv;
        xv.w = 0.f;
        ((float4*)xs4)[gnode] = xv;
    }
    lcnt[t] = 0;
    __syncthreads();
#pragma unroll
    for (int k = 0; k < KPT; ++k) {
        int e = e0 + t + k * 256;
        if (e < e1) {
            unsigned int key = kc[k];
            int ld = key >> 18;
            int pos = atomicAdd(&lcnt[ld], 1);
            csr[e0 + lpre[ld] + pos] = (int)(key & 0x3FFFFu);
        }
    }
}

// ---------------------------------------------------------------------------
// K3: layer-1 z-gather, 2 threads/node (halved load imbalance): each lane of
// a pair walks half the neighbor list; pair-combine via __shfl_down (same
// wave, no sync); even lane scales by dinv, stores z, and does moment stats.
// ---------------------------------------------------------------------------
__global__ __launch_bounds__(256) void k_gz(
        const float* __restrict__ xs4, const int* __restrict__ csr,
        const unsigned int* __restrict__ rowptr, const float* __restrict__ dinv,
        const int* __restrict__ batch,
        float* __restrict__ zs4, float* __restrict__ gstats) {
    __shared__ float st[8 * 12];
    __shared__ int gbase_s;
    int t = threadIdx.x;
    for (int i = t; i < 8 * 12; i += 256) st[i] = 0.f;
    if (t == 0) gbase_s = batch[blockIdx.x * 128];
    __syncthreads();

    int gid = blockIdx.x * 256 + t;
    int n = gid >> 1, h = gid & 1;
    float z0 = 0.f, z1 = 0.f, z2 = 0.f;
    if (n < N_NODES) {
        const float4* xv = (const float4*)xs4;
        unsigned int rp = rowptr[n];
        int st0 = (int)(rp >> 8);
        int len = (int)(rp & 255u);
        int half0 = (len + 1) >> 1;
        int e  = h ? (st0 + half0) : st0;
        int e1 = h ? (st0 + len)   : (st0 + half0);
        if (!h) {
            float4 sv = xv[n];           // self term on even lane only
            z0 = sv.x; z1 = sv.y; z2 = sv.z;
        }
        for (; e + 3 < e1; e += 4) {
            int s0 = csr[e], s1 = csr[e + 1], s2 = csr[e + 2], s3 = csr[e + 3];
            float4 u0 = xv[s0], u1 = xv[s1], u2 = xv[s2], u3 = xv[s3];
            z0 += u0.x + u1.x + u2.x + u3.x;
            z1 += u0.y + u1.y + u2.y + u3.y;
            z2 += u0.z + u1.z + u2.z + u3.z;
        }
        for (; e < e1; ++e) {
            float4 u = xv[csr[e]];
            z0 += u.x; z1 += u.y; z2 += u.z;
        }
    }
    // pair reduce (lanes 2k <- 2k+1)
    z0 += __shfl_down(z0, 1);
    z1 += __shfl_down(z1, 1);
    z2 += __shfl_down(z2, 1);
    if (h == 0 && n < N_NODES) {
        float dd = dinv[n];
        z0 *= dd; z1 *= dd; z2 *= dd;
        float4 zv; zv.x = z0; zv.y = z1; zv.z = z2; zv.w = 0.f;
        ((float4*)zs4)[n] = zv;
        int g = batch[n];
        int lg = g - gbase_s;
        if (lg < 8) {
            float* sp = &st[lg * 12];
            atomicAdd(&sp[0], z0);      atomicAdd(&sp[1], z1);
            atomicAdd(&sp[2], z2);      atomicAdd(&sp[3], z0 * z0);
            atomicAdd(&sp[4], z0 * z1); atomicAdd(&sp[5], z0 * z2);
            atomicAdd(&sp[6], z1 * z1); atomicAdd(&sp[7], z1 * z2);
            atomicAdd(&sp[8], z2 * z2);
        } else {
            float* gp = &gstats[g * 9];
            atomicAdd(&gp[0], z0);      atomicAdd(&gp[1], z1);
            atomicAdd(&gp[2], z2);      atomicAdd(&gp[3], z0 * z0);
            atomicAdd(&gp[4], z0 * z1); atomicAdd(&gp[5], z0 * z2);
            atomicAdd(&gp[6], z1 * z1); atomicAdd(&gp[7], z1 * z2);
            atomicAdd(&gp[8], z2 * z2);
        }
    }
    __syncthreads();
    if (t < 72) {
        int slot = t / 9, k = t % 9;
        int g = gbase_s + slot;
        float v = st[slot * 12 + k];
        if (g < N_GRAPHS && v != 0.f) atomicAdd(&gstats[g * 9 + k], v);
    }
}

// ---------------------------------------------------------------------------
// K4: analytic GN1 per-(graph,feature) stats from z moments.
// ---------------------------------------------------------------------------
__global__ __launch_bounds__(256) void k_prep(
        const float* __restrict__ gstats, const int* __restrict__ off,
        const float* __restrict__ W, const float* __restrict__ bias,
        const float* __restrict__ gw, const float* __restrict__ gms,
        float* __restrict__ mvA, float* __restrict__ scA) {
    int gid = blockIdx.x * 256 + threadIdx.x;
    if (gid >= N_GRAPHS * F) return;
    int g = gid >> 5, f = gid & 31;
    float rc = 1.0f / (float)(off[g + 1] - off[g]);
    const float* sp = &gstats[g * 9];
    float S0 = sp[0], S1 = sp[1], S2 = sp[2];
    float m00 = sp[3], m01 = sp[4], m02 = sp[5], m11 = sp[6], m12 = sp[7], m22 = sp[8];
    float w0 = W[0 * F + f], w1 = W[1 * F + f], w2 = W[2 * F + f];
    float b = bias[f];
    float sy = w0 * S0 + w1 * S1 + w2 * S2;
    float m = sy * rc + b;
    float q = w0 * w0 * m00 + w1 * w1 * m11 + w2 * w2 * m22
            + 2.f * (w0 * w1 * m01 + w0 * w2 * m02 + w1 * w2 * m12);
    float Ey2 = q * rc + 2.f * b * (sy * rc) + b * b;
    float mv = gms[f] * m;
    float var = Ey2 - 2.f * mv * m + mv * mv;
    mvA[gid] = mv;
    scA[gid] = gw[f] * rsqrtf(var + EPSV);
}

// ---------------------------------------------------------------------------
// K5: layer-1 elementwise: y=z@W1+b1 -> normalize -> ReLU -> x1 + bf16 xh.
// ---------------------------------------------------------------------------
__global__ __launch_bounds__(256) void k_n1(
        const float* __restrict__ zs4, const int* __restrict__ batch,
        const float* __restrict__ dinv,
        const float* __restrict__ W, const float* __restrict__ bias,
        const float* __restrict__ gb,
        const float* __restrict__ mvA, const float* __restrict__ scA,
        unsigned short* __restrict__ xh, float* __restrict__ outp) {
    int gid = blockIdx.x * 256 + threadIdx.x;
    int n = gid >> 3, c = gid & 7;
    if (n >= N_NODES) return;
    float4 zv = ((const float4*)zs4)[n];
    float z0 = zv.x, z1 = zv.y, z2 = zv.z;
    int g = batch[n];
    float dd = dinv[n];
    float4 w0 = ((const float4*)(W + 0 * F))[c];
    float4 w1 = ((const float4*)(W + 1 * F))[c];
    float4 w2 = ((const float4*)(W + 2 * F))[c];
    float4 y  = ((const float4*)bias)[c];
    y.x += z0 * w0.x + z1 * w1.x + z2 * w2.x;
    y.y += z0 * w0.y + z1 * w1.y + z2 * w2.y;
    y.z += z0 * w0.z + z1 * w1.z + z2 * w2.z;
    y.w += z0 * w0.w + z1 * w1.w + z2 * w2.w;
    float4 mv = ((const float4*)mvA)[g * 8 + c];
    float4 sc = ((const float4*)scA)[g * 8 + c];
    float4 bb = ((const float4*)gb)[c];
    float4 o;
    o.x = fmaxf((y.x - mv.x) * sc.x + bb.x, 0.f);
    o.y = fmaxf((y.y - mv.y) * sc.y + bb.y, 0.f);
    o.z = fmaxf((y.z - mv.z) * sc.z + bb.z, 0.f);
    o.w = fmaxf((y.w - mv.w) * sc.w + bb.w, 0.f);
    ((float4*)outp)[n * 8 + c] = o;
    uint2 hp;
    hp.x = f2bf(o.x * dd) | (f2bf(o.y * dd) << 16);
    hp.y = f2bf(o.z * dd) | (f2bf(o.w * dd) << 16);
    ((uint2*)xh)[n * 8 + c] = hp;
}

// ---------------------------------------------------------------------------
// K6: aggregate(32-wide bf16 rows, self from xh) + transform(32->32) + bias.
// 4 threads/node, scalar csr loads, 4x-unrolled edge loop, packed rowptr.
// (measured-best combo — do not restructure; R7/R8/R12 all regressed it)
// ---------------------------------------------------------------------------
__global__ __launch_bounds__(256) void k_gat32(
        const unsigned short* __restrict__ xh, const int* __restrict__ csr,
        const unsigned int* __restrict__ rowptr, const float* __restrict__ dinv,
        const float* __restrict__ W, const float* __restrict__ bias,
        float* __restrict__ y) {
    __shared__ float Ws[F * F];     // 4 KB
    __shared__ float bs[F];
    __shared__ float Zs[64 * 36];   // 9 KB
    int t = threadIdx.x;
    ((float4*)Ws)[t] = ((const float4*)W)[t];
    if (t < F) bs[t] = bias[t];
    __syncthreads();

    int gid = blockIdx.x * 256 + t;
    int n = gid >> 2, c = gid & 3, ln = t >> 2;
    bool act = (n < N_NODES);
    float acc[8];
    if (act) {
        const uint4* xr = (const uint4*)xh;  // row = 4 x 16B
        uint4 us = xr[n * 4 + c];            // self: dd^2*x = dd*xh
        acc[0] = bflo(us.x); acc[1] = bfhi(us.x);
        acc[2] = bflo(us.y); acc[3] = bfhi(us.y);
        acc[4] = bflo(us.z); acc[5] = bfhi(us.z);
        acc[6] = bflo(us.w); acc[7] = bfhi(us.w);
        unsigned int rp = rowptr[n];
        int e = (int)(rp >> 8);
        int e1 = e + (int)(rp & 255u);
        for (; e + 3 < e1; e += 4) {
            int s0 = csr[e], s1 = csr[e + 1], s2 = csr[e + 2], s3 = csr[e + 3];
            uint4 u0 = xr[s0 * 4 + c];
            uint4 u1 = xr[s1 * 4 + c];
            uint4 u2 = xr[s2 * 4 + c];
            uint4 u3 = xr[s3 * 4 + c];
            acc[0] += bflo(u0.x); acc[1] += bfhi(u0.x);
            acc[2] += bflo(u0.y); acc[3] += bfhi(u0.y);
            acc[4] += bflo(u0.z); acc[5] += bfhi(u0.z);
            acc[6] += bflo(u0.w); acc[7] += bfhi(u0.w);
            acc[0] += bflo(u1.x); acc[1] += bfhi(u1.x);
            acc[2] += bflo(u1.y); acc[3] += bfhi(u1.y);
            acc[4] += bflo(u1.z); acc[5] += bfhi(u1.z);
            acc[6] += bflo(u1.w); acc[7] += bfhi(u1.w);
            acc[0] += bflo(u2.x); acc[1] += bfhi(u2.x);
            acc[2] += bflo(u2.y); acc[3] += bfhi(u2.y);
            acc[4] += bflo(u2.z); acc[5] += bfhi(u2.z);
            acc[6] += bflo(u2.w); acc[7] += bfhi(u2.w);
            acc[0] += bflo(u3.x); acc[1] += bfhi(u3.x);
            acc[2] += bflo(u3.y); acc[3] += bfhi(u3.y);
            acc[4] += bflo(u3.z); acc[5] += bfhi(u3.z);
            acc[6] += bflo(u3.w); acc[7] += bfhi(u3.w);
        }
        for (; e < e1; ++e) {
            int s0 = csr[e];
            uint4 u0 = xr[s0 * 4 + c];
            acc[0] += bflo(u0.x); acc[1] += bfhi(u0.x);
            acc[2] += bflo(u0.y); acc[3] += bfhi(u0.y);
            acc[4] += bflo(u0.z); acc[5] += bfhi(u0.z);
            acc[6] += bflo(u0.w); acc[7] += bfhi(u0.w);
        }
        float dd = dinv[n];
#pragma unroll
        for (int j = 0; j < 8; ++j) acc[j] *= dd;
    } else {
#pragma unroll
        for (int j = 0; j < 8; ++j) acc[j] = 0.f;
    }
    *(float4*)&Zs[ln * 36 + c * 8]     = *(float4*)&acc[0];
    *(float4*)&Zs[ln * 36 + c * 8 + 4] = *(float4*)&acc[4];
    __syncthreads();

    if (act) {
        const float* zrow = &Zs[ln * 36];
        float4 o0 = ((const float4*)bs)[c * 2];
        float4 o1 = ((const float4*)bs)[c * 2 + 1];
#pragma unroll
        for (int k = 0; k < F; ++k) {
            float zk = zrow[k];
            float4 w0 = ((const float4*)&Ws[k * F])[c * 2];
            float4 w1 = ((const float4*)&Ws[k * F])[c * 2 + 1];
            o0.x += zk * w0.x; o0.y += zk * w0.y; o0.z += zk * w0.z; o0.w += zk * w0.w;
            o1.x += zk * w1.x; o1.y += zk * w1.y; o1.z += zk * w1.z; o1.w += zk * w1.w;
        }
        ((float4*)y)[n * 8 + c * 2]     = o0;
        ((float4*)y)[n * 8 + c * 2 + 1] = o1;
    }
}

// ---------------------------------------------------------------------------
// K7: GraphNorm, block per graph; single-pass stats, normalize pass L2-hot.
// In-place capable. Emits fp32 out + (WXH) bf16 dinv-pre-scaled xh.
// ---------------------------------------------------------------------------
template <bool RES, bool WXH>
__global__ __launch_bounds__(256) void k_gn2(
        const float* agg, const float* res, const int* __restrict__ off,
        const float* __restrict__ gw, const float* __restrict__ gb,
        const float* __restrict__ gms, const float* __restrict__ dinv,
        unsigned short* __restrict__ xh, float* outp) {
    __shared__ float red1[256], red2[256];
    __shared__ float mv_s[F], sc_s[F];
    int g = blockIdx.x;
    int i0 = off[g], i1 = off[g + 1];
    float rc = 1.0f / (float)(i1 - i0);
    int t = threadIdx.x;
    int f = t & 31, r0 = t >> 5;

    float s = 0.f, q = 0.f;
    for (int n = i0 + r0; n < i1; n += 8) {
        float v = agg[n * F + f];
        s += v; q += v * v;
    }
    red1[t] = s; red2[t] = q; __syncthreads();
    if (t < 128) { red1[t] += red1[t + 128]; red2[t] += red2[t + 128]; } __syncthreads();
    if (t < 64)  { red1[t] += red1[t + 64];  red2[t] += red2[t + 64];  } __syncthreads();
    if (t < 32) {
        float sm = (red1[t] + red1[t + 32]) * rc;
        float sq = (red2[t] + red2[t + 32]) * rc;
        float mv = gms[t] * sm;
        float var = sq - mv * (2.f * sm - mv);
        mv_s[t] = mv;
        sc_s[t] = gw[t] * rsqrtf(var + EPSV);
    }
    __syncthreads();

    float w = sc_s[f], mv = mv_s[f], bb = gb[f];
    for (int n = i0 + r0; n < i1; n += 8) {
        float y = (agg[n * F + f] - mv) * w + bb;
        if (RES) y += res[n * F + f];
        y = fmaxf(y, 0.f);
        outp[n * F + f] = y;
        if (WXH) xh[n * F + f] = (unsigned short)f2bf(y * dinv[n]);
    }
}

// ---------------------------------------------------------------------------
// K8: final GraphNorm + residual + ReLU + mean-pool + 32x3 linear
// ---------------------------------------------------------------------------
__global__ __launch_bounds__(256) void k_gnfin(
        const float* __restrict__ agg, const float* __restrict__ res,
        const int* __restrict__ off,
        const float* __restrict__ gw, const float* __restrict__ gb,
        const float* __restrict__ gms,
        const float* __restrict__ lin_w, const float* __restrict__ lin_b,
        float* __restrict__ outp) {
    __shared__ float red1[256], red2[256];
    __shared__ float mv_s[F], sc_s[F], pooled_s[F];
    int g = blockIdx.x;
    int i0 = off[g], i1 = off[g + 1];
    float cnt = (float)(i1 - i0);
    float rc = 1.0f / cnt;
    int t = threadIdx.x;
    int f = t & 31, r0 = t >> 5;

    float s = 0.f, q = 0.f;
    for (int n = i0 + r0; n < i1; n += 8) {
        float v = agg[n * F + f];
        s += v; q += v * v;
    }
    red1[t] = s; red2[t] = q; __syncthreads();
    if (t < 128) { red1[t] += red1[t + 128]; red2[t] += red2[t + 128]; } __syncthreads();
    if (t < 64)  { red1[t] += red1[t + 64];  red2[t] += red2[t + 64];  } __syncthreads();
    if (t < 32) {
        float sm = (red1[t] + red1[t + 32]) * rc;
        float sq = (red2[t] + red2[t + 32]) * rc;
        float mv = gms[t] * sm;
        float var = sq - mv * (2.f * sm - mv);
        mv_s[t] = mv;
        sc_s[t] = gw[t] * rsqrtf(var + EPSV);
    }
    __syncthreads();

    float w = sc_s[f], mv = mv_s[f], bb = gb[f];
    float ps = 0.f;
    for (int n = i0 + r0; n < i1; n += 8) {
        float yv = (agg[n * F + f] - mv) * w + bb + res[n * F + f];
        ps += fmaxf(yv, 0.f);
    }
    __syncthreads();
    red1[t] = ps; __syncthreads();
    if (t < 128) red1[t] += red1[t + 128]; __syncthreads();
    if (t < 64)  red1[t] += red1[t + 64];  __syncthreads();
    if (t < 32) { red1[t] += red1[t + 32]; pooled_s[t] = red1[t] * rc; }
    __syncthreads();
    if (t < 3) {
        float o = lin_b[t];
#pragma unroll
        for (int f2 = 0; f2 < F; ++f2) o += pooled_s[f2] * lin_w[f2 * 3 + t];
        outp[g * 3 + t] = o;
    }
}

// ---------------------------------------------------------------------------
extern "C" void kernel_launch(void* const* d_in, const int* in_sizes, int n_in,
                              void* d_out, int out_size, void* d_ws, size_t ws_size,
                              hipStream_t stream) {
    const float* x      = (const float*)d_in[0];
    const int*   ei     = (const int*)d_in[1];
    const int*   batch  = (const int*)d_in[2];
    const float* W1     = (const float*)d_in[3];
    const float* b1     = (const float*)d_in[4];
    const float* gn1w   = (const float*)d_in[5];
    const float* gn1b   = (const float*)d_in[6];
    const float* gn1ms  = (const float*)d_in[7];
    const float* W2     = (const float*)d_in[8];
    const float* b2     = (const float*)d_in[9];
    const float* gn2w   = (const float*)d_in[10];
    const float* gn2b   = (const float*)d_in[11];
    const float* gn2ms  = (const float*)d_in[12];
    const float* W3     = (const float*)d_in[13];
    const float* b3     = (const float*)d_in[14];
    const float* gn3w   = (const float*)d_in[15];
    const float* gn3b   = (const float*)d_in[16];
    const float* gn3ms  = (const float*)d_in[17];
    const float* lin_w  = (const float*)d_in[18];
    const float* lin_b  = (const float*)d_in[19];
    float* out = (float*)d_out;

    const int* srcp = ei;
    const int* dstp = ei + N_EDGES;

    char* ws = (char*)d_ws;
    size_t p = 0;
    auto alloc = [&](size_t bytes) {
        size_t r = p; p += (bytes + 511) & ~(size_t)511; return r;
    };
    int*   off       = (int*)  (ws + alloc(sizeof(int) * (N_GRAPHS + 1)));
    int*   bucketCur = (int*)  (ws + alloc(sizeof(int) * NB));
    unsigned int* rowptr = (unsigned int*)(ws + alloc(sizeof(unsigned int) * N_NODES));
    float* dinv      = (float*)(ws + alloc(sizeof(float) * N_NODES));
    float* xs4       = (float*)(ws + alloc(sizeof(float) * N_NODES * 4));
    float* zs4       = (float*)(ws + alloc(sizeof(float) * N_NODES * 4));
    float* gstats    = (float*)(ws + alloc(sizeof(float) * N_GRAPHS * 9));
    float* mvA       = (float*)(ws + alloc(sizeof(float) * N_GRAPHS * F));
    float* scA       = (float*)(ws + alloc(sizeof(float) * N_GRAPHS * F));
    unsigned int* binned = (unsigned int*)(ws + alloc(sizeof(unsigned int) * NB * CAP));
    int*   csr       = (int*)  (ws + alloc(sizeof(int) * NB * CAP));
    float* A         = (float*)(ws + alloc(sizeof(float) * N_NODES * F));
    float* B         = (float*)(ws + alloc(sizeof(float) * N_NODES * F));
    // xh aliases binned (dead after k_csr); xh 9.6 MB <= binned 12 MB.
    unsigned short* xh = (unsigned short*)binned;
    (void)ws_size; (void)n_in; (void)in_sizes; (void)out_size;

    const int TB = 256;
    dim3 blk(TB);
    int ngrid  = (N_NODES + TB - 1) / TB;
    int ggrid2 = (N_NODES * 2 + TB - 1) / TB;
    int ggrid8 = (N_NODES * 8 + TB - 1) / TB;
    int ggrid4 = (N_NODES * 4 + TB - 1) / TB;

    // build: init (off, cursors, gstats) -> bin (fixed-cap buckets) -> csr
    k_init<<<ngrid, blk, 0, stream>>>(batch, bucketCur, off, gstats);
    k_bin <<<NEB, blk, 0, stream>>>(srcp, dstp, bucketCur, binned);
    k_csr <<<NB, blk, 0, stream>>>(binned, bucketCur, x, rowptr, dinv, xs4, csr);

    // layer 1 (analytic GN stats from 3-dim z moments)
    k_gz  <<<ggrid2, blk, 0, stream>>>(xs4, csr, rowptr, dinv, batch, zs4, gstats);
    k_prep<<<(N_GRAPHS * F + TB - 1) / TB, blk, 0, stream>>>(
        gstats, off, W1, b1, gn1w, gn1ms, mvA, scA);
    k_n1  <<<ggrid8, blk, 0, stream>>>(zs4, batch, dinv, W1, b1, gn1b, mvA, scA, xh, A);

    // layer 2: gather(xh)+transform -> B ; GN + res(A) in-place -> x2=B (+ xh)
    k_gat32<<<ggrid4, blk, 0, stream>>>(xh, csr, rowptr, dinv, W2, b2, B);
    k_gn2<true, true><<<N_GRAPHS, blk, 0, stream>>>(
        B, A, off, gn2w, gn2b, gn2ms, dinv, xh, B);

    // layer 3: gather(xh)+transform -> A ; GN + res(B) + pool + linear -> out
    k_gat32<<<ggrid4, blk, 0, stream>>>(xh, csr, rowptr, dinv, W3, b3, A);
    k_gnfin<<<N_GRAPHS, blk, 0, stream>>>(A, B, off, gn3w, gn3b, gn3ms,
                                          lin_w, lin_b, out);
}